// Round 1
// baseline (5397.925 us; speedup 1.0000x reference)
//
#include <hip/hip_runtime.h>
#include <hip/hip_bf16.h>

#define BB 8
#define NN 1024
#define DD 768
#define HH 12
#define DKVX 64
#define DFF 3072
#define EE 16
#define CAPX 128
#define NT (BB*NN)   // 8192 tokens

typedef __attribute__((ext_vector_type(8))) short bf16x8;
typedef __attribute__((ext_vector_type(4))) float f32x4;

__device__ __forceinline__ float b2f(__hip_bfloat16 x) { return __bfloat162float(x); }
__device__ __forceinline__ __hip_bfloat16 f2b(float x) { return __float2bfloat16(x); }
__device__ __forceinline__ float toFloat(float x) { return x; }
__device__ __forceinline__ float toFloat(__hip_bfloat16 x) { return __bfloat162float(x); }

// ---- 8-element vector loads (16B for bf16, 32B for float) ----
__device__ __forceinline__ void load8(const __hip_bfloat16* p, float* dst) {
    uint4 u = *reinterpret_cast<const uint4*>(p);
    const __hip_bfloat16* hb = reinterpret_cast<const __hip_bfloat16*>(&u);
#pragma unroll
    for (int i = 0; i < 8; ++i) dst[i] = b2f(hb[i]);
}
__device__ __forceinline__ void load8(const float* p, float* dst) {
    float4 a = reinterpret_cast<const float4*>(p)[0];
    float4 b = reinterpret_cast<const float4*>(p)[1];
    dst[0]=a.x; dst[1]=a.y; dst[2]=a.z; dst[3]=a.w;
    dst[4]=b.x; dst[5]=b.y; dst[6]=b.z; dst[7]=b.w;
}
__device__ __forceinline__ void storeC(float* p, float v) { *p = v; }
__device__ __forceinline__ void storeC(__hip_bfloat16* p, float v) { *p = f2b(v); }

// ---- RMSNorm (T5): out fp32 = x * rsqrt(mean(x^2)+1e-6) * w ----
template<typename TIN>
__global__ __launch_bounds__(256) void rmsnorm_k(const TIN* __restrict__ x,
                                                 const float* __restrict__ w,
                                                 float* __restrict__ out) {
    int t = blockIdx.x;
    int tid = threadIdx.x;
    const TIN* xp = x + (size_t)t * DD;
    float xv[3];
    float s = 0.f;
#pragma unroll
    for (int i = 0; i < 3; ++i) {
        float v = toFloat(xp[tid + i*256]);
        xv[i] = v; s += v*v;
    }
#pragma unroll
    for (int off = 1; off < 64; off <<= 1) s += __shfl_xor(s, off);
    __shared__ float sm[8];
    int wv = tid >> 6, ln = tid & 63;
    if (ln == 0) sm[wv] = s;
    __syncthreads();
    if (tid == 0) {
        float tot = sm[0]+sm[1]+sm[2]+sm[3];
        sm[4] = 1.0f / sqrtf(tot / (float)DD + 1e-6f);
    }
    __syncthreads();
    float sc = sm[4];
    float* op = out + (size_t)t * DD;
#pragma unroll
    for (int i = 0; i < 3; ++i) {
        int d = tid + i*256;
        op[d] = xv[i] * sc * w[d];
    }
}

// ---- Generic tiled GEMM (fp32 VALU path for the routing-critical projections):
// C[M,N] = A[M,K] @ B[K,N]; fp32 accum. 128x128 tile, BK=16, 256 threads, 8x8/thread.
template<typename TA, typename TB, typename TC, bool RELU, bool RESID>
__global__ __launch_bounds__(256) void gemm_k(const TA* __restrict__ A,
                                              const TB* __restrict__ B,
                                              TC* __restrict__ C,
                                              const float* __restrict__ R,
                                              int M, int N, int K,
                                              long sA, long sB, long sC) {
    __shared__ float As[16][132];
    __shared__ float Bs[16][132];
    const int bz = blockIdx.z;
    A += (size_t)bz * sA; B += (size_t)bz * sB; C += (size_t)bz * sC;
    const int row0 = blockIdx.y * 128, col0 = blockIdx.x * 128;
    const int tid = threadIdx.x;
    const int tx = tid & 15, ty = tid >> 4;
    const int ar = tid >> 1, ak = (tid & 1) * 8;   // A loader: row, k-offset
    const int bk = tid >> 4, bc = (tid & 15) * 8;  // B loader: k-row, col-offset
    float acc[8][8] = {};
    for (int k0 = 0; k0 < K; k0 += 16) {
        float av[8], bv[8];
        load8(A + (size_t)(row0 + ar) * K + (k0 + ak), av);
        load8(B + (size_t)(k0 + bk) * N + (col0 + bc), bv);
#pragma unroll
        for (int j = 0; j < 8; ++j) As[ak + j][ar] = av[j];
#pragma unroll
        for (int j = 0; j < 8; ++j) Bs[bk][bc + j] = bv[j];
        __syncthreads();
#pragma unroll
        for (int kk = 0; kk < 16; ++kk) {
            float a[8], b[8];
#pragma unroll
            for (int i = 0; i < 8; ++i) a[i] = As[kk][ty*8 + i];
#pragma unroll
            for (int j = 0; j < 8; ++j) b[j] = Bs[kk][tx*8 + j];
#pragma unroll
            for (int i = 0; i < 8; ++i)
#pragma unroll
                for (int j = 0; j < 8; ++j)
                    acc[i][j] += a[i] * b[j];
        }
        __syncthreads();
    }
#pragma unroll
    for (int i = 0; i < 8; ++i) {
        int r = row0 + ty*8 + i;
#pragma unroll
        for (int j = 0; j < 8; ++j) {
            int c = col0 + tx*8 + j;
            float v = acc[i][j];
            if (RESID) v += R[(size_t)r * N + c];
            if (RELU)  v = fmaxf(v, 0.f);
            storeC(C + (size_t)r * N + c, v);
        }
    }
}

// ---- Transpose + fp32->bf16 convert: in [K][N] fp32 -> out [N][K] bf16, batched z ----
__global__ __launch_bounds__(256) void transpose_cvt_k(const float* __restrict__ in,
                                                       __hip_bfloat16* __restrict__ outT,
                                                       int K, int N) {
    __shared__ float tile[32][33];
    const int z = blockIdx.z;
    in   += (size_t)z * K * N;
    outT += (size_t)z * K * N;
    const int n0 = blockIdx.x * 32, k0 = blockIdx.y * 32;
    const int tx = threadIdx.x & 31, ty = threadIdx.x >> 5;  // 32x8
#pragma unroll
    for (int i = 0; i < 4; ++i)
        tile[ty + 8*i][tx] = in[(size_t)(k0 + ty + 8*i) * N + n0 + tx];
    __syncthreads();
#pragma unroll
    for (int i = 0; i < 4; ++i)
        outT[(size_t)(n0 + ty + 8*i) * K + k0 + tx] = f2b(tile[tx][ty + 8*i]);
}

// ---- MFMA bf16 GEMM: C[M,N](bf16) = A[M,K](bf16) @ Bt[N,K](bf16)^T, batched z.
// 128x128 tile, BK=32, 256 threads = 4 waves (2x2), wave tile 64x64 = 4x4 frags of
// 16x16 via v_mfma_f32_16x16x32_bf16. LDS stride 40 bf16 (80 B) -> 2-way max bank
// aliasing on ds_read_b128 (free). Register prefetch double-buffer on staging.
template<bool RELU>
__global__ __launch_bounds__(256) void gemm_mfma_k(const __hip_bfloat16* __restrict__ A,
                                                   const __hip_bfloat16* __restrict__ Bt,
                                                   __hip_bfloat16* __restrict__ C,
                                                   int M, int N, int K,
                                                   long sA, long sB, long sC) {
    __shared__ unsigned short As[128][40];
    __shared__ unsigned short Bs[128][40];
    const int z = blockIdx.z;
    A  += (size_t)z * sA;
    Bt += (size_t)z * sB;
    C  += (size_t)z * sC;
    const int row0 = blockIdx.y * 128, col0 = blockIdx.x * 128;
    const int tid = threadIdx.x;
    const int lane = tid & 63, wid = tid >> 6;
    const int wr = (wid >> 1) * 64, wc = (wid & 1) * 64;   // wave tile origin
    const int lr = lane & 15, lkg = lane >> 4;             // frag row/col, k-group
    const int srow = tid >> 1, skh = (tid & 1) * 16;       // staging: row, k-half

    const __hip_bfloat16* Ag = A  + (size_t)(row0 + srow) * K + skh;
    const __hip_bfloat16* Bg = Bt + (size_t)(col0 + srow) * K + skh;

    f32x4 acc[4][4] = {};
    // prefetch k0 = 0
    uint4 a0 = *(const uint4*)(Ag);
    uint4 a1 = *(const uint4*)(Ag + 8);
    uint4 b0 = *(const uint4*)(Bg);
    uint4 b1 = *(const uint4*)(Bg + 8);
    for (int k0 = 0; k0 < K; k0 += 32) {
        __syncthreads();   // previous iteration's frag reads done
        *(uint4*)&As[srow][skh]     = a0;
        *(uint4*)&As[srow][skh + 8] = a1;
        *(uint4*)&Bs[srow][skh]     = b0;
        *(uint4*)&Bs[srow][skh + 8] = b1;
        __syncthreads();
        if (k0 + 32 < K) {  // issue next-tile loads; latency hides under MFMA
            a0 = *(const uint4*)(Ag + k0 + 32);
            a1 = *(const uint4*)(Ag + k0 + 40);
            b0 = *(const uint4*)(Bg + k0 + 32);
            b1 = *(const uint4*)(Bg + k0 + 40);
        }
        bf16x8 af[4], bfr[4];
#pragma unroll
        for (int m = 0; m < 4; ++m)
            af[m] = *(const bf16x8*)&As[wr + m*16 + lr][lkg*8];
#pragma unroll
        for (int n = 0; n < 4; ++n)
            bfr[n] = *(const bf16x8*)&Bs[wc + n*16 + lr][lkg*8];
#pragma unroll
        for (int m = 0; m < 4; ++m)
#pragma unroll
            for (int n = 0; n < 4; ++n)
                acc[m][n] = __builtin_amdgcn_mfma_f32_16x16x32_bf16(af[m], bfr[n], acc[m][n], 0, 0, 0);
    }
    // C/D layout: col = lane&15, row = (lane>>4)*4 + reg  [m89/m91 verified]
#pragma unroll
    for (int m = 0; m < 4; ++m) {
#pragma unroll
        for (int n = 0; n < 4; ++n) {
#pragma unroll
            for (int r = 0; r < 4; ++r) {
                int rr = row0 + wr + m*16 + lkg*4 + r;
                int cc = col0 + wc + n*16 + lr;
                float v = acc[m][n][r];
                if (RELU) v = fmaxf(v, 0.f);
                C[(size_t)rr * N + cc] = f2b(v);
            }
        }
    }
}

// ---- Attention: one wave per (b,h,query row). No scaling (T5), mask all-true.
__global__ __launch_bounds__(256) void attn_k(const float* __restrict__ q,
                                              const float* __restrict__ k,
                                              const float* __restrict__ v,
                                              float* __restrict__ ctx) {
    __shared__ float sc[4][NN];
    __shared__ float qs[4][DKVX];
    int wave = threadIdx.x >> 6, lane = threadIdx.x & 63;
    int blk = blockIdx.x;
    int qt = blk & 255; int bh = blk >> 8;
    int h = bh % HH; int b = bh / HH;
    int qi = qt * 4 + wave;
    size_t base = (size_t)b * NN * DD + (size_t)h * DKVX;
    qs[wave][lane] = q[base + (size_t)qi * DD + lane];
    __syncthreads();
    float m = -1e30f;
    float sv[16];
#pragma unroll
    for (int it = 0; it < 16; ++it) {
        int j = lane + it * 64;
        const float4* kp = (const float4*)(k + base + (size_t)j * DD);
        float s = 0.f;
#pragma unroll
        for (int d4 = 0; d4 < 16; ++d4) {
            float4 kv = kp[d4];
            s += qs[wave][d4*4+0]*kv.x + qs[wave][d4*4+1]*kv.y
               + qs[wave][d4*4+2]*kv.z + qs[wave][d4*4+3]*kv.w;
        }
        sv[it] = s;
        m = fmaxf(m, s);
    }
#pragma unroll
    for (int off = 1; off < 64; off <<= 1) m = fmaxf(m, __shfl_xor(m, off));
    float ssum = 0.f;
#pragma unroll
    for (int it = 0; it < 16; ++it) {
        float e = expf(sv[it] - m);
        sc[wave][lane + it*64] = e;
        ssum += e;
    }
#pragma unroll
    for (int off = 1; off < 64; off <<= 1) ssum += __shfl_xor(ssum, off);
    float inv = 1.0f / ssum;
    __syncthreads();
    float acc = 0.f;
    const float* vp = v + base + lane;
#pragma unroll 8
    for (int j = 0; j < NN; ++j) {
        acc += sc[wave][j] * vp[(size_t)j * DD];
    }
    ctx[base + (size_t)qi * DD + lane] = acc * inv;
}

// ---- Gate: logits -> softmax -> top2 (+normalized gates), proxy/density accum
__global__ __launch_bounds__(256) void gate_k(const float* __restrict__ x,
                                              const float* __restrict__ gw,
                                              int* __restrict__ idx1, int* __restrict__ idx2,
                                              float* __restrict__ g1n, float* __restrict__ g2n,
                                              float* __restrict__ proxy, float* __restrict__ cnt1) {
    __shared__ float gws[DD*EE];
    for (int i = threadIdx.x; i < DD*EE; i += 256) gws[i] = gw[i];
    __syncthreads();
    int t = blockIdx.x * 256 + threadIdx.x;
    int b = t >> 10;
    float acc[EE] = {};
    const float4* xp = (const float4*)(x + (size_t)t * DD);
    for (int d4 = 0; d4 < DD/4; ++d4) {
        float4 xv = xp[d4];
        float xs[4] = {xv.x, xv.y, xv.z, xv.w};
#pragma unroll
        for (int qq = 0; qq < 4; ++qq) {
            const float* g = &gws[(d4*4+qq)*EE];
#pragma unroll
            for (int e = 0; e < EE; ++e) acc[e] += xs[qq] * g[e];
        }
    }
    // softmax over 16
    float m = acc[0];
#pragma unroll
    for (int e = 1; e < EE; ++e) m = fmaxf(m, acc[e]);
    float sum = 0.f;
    float raw[EE];
#pragma unroll
    for (int e = 0; e < EE; ++e) { raw[e] = expf(acc[e] - m); sum += raw[e]; }
    float inv = 1.0f / sum;
#pragma unroll
    for (int e = 0; e < EE; ++e) raw[e] *= inv;
    // top-1 (first occurrence on ties, like jnp.argmax)
    int i1 = 0; float p1 = raw[0];
#pragma unroll
    for (int e = 1; e < EE; ++e) if (raw[e] > p1) { p1 = raw[e]; i1 = e; }
    // top-2 among the rest
    int i2 = (i1 == 0) ? 1 : 0; float p2 = raw[i2];
#pragma unroll
    for (int e = 0; e < EE; ++e) if (e != i1 && raw[e] > p2) { p2 = raw[e]; i2 = e; }
    float den = p1 + p2 + 1e-9f;
    idx1[t] = i1; idx2[t] = i2;
    g1n[t] = p1 / den; g2n[t] = p2 / den;
    // wave-reduced atomics: proxy (softmax sums) and density counts
    int ln = threadIdx.x & 63;
#pragma unroll
    for (int e = 0; e < EE; ++e) {
        float r = raw[e];
#pragma unroll
        for (int off = 1; off < 64; off <<= 1) r += __shfl_xor(r, off);
        if (ln == 0) atomicAdd(&proxy[b*EE + e], r);
    }
#pragma unroll
    for (int e = 0; e < EE; ++e) {
        unsigned long long mb = __ballot(i1 == e);
        if (ln == 0 && mb) atomicAdd(&cnt1[b*EE + e], (float)__popcll(mb));
    }
}

// ---- Capacity: literal sequential scan per (b,e). 128 threads total.
__global__ void capacity_k(const int* __restrict__ idx1, const int* __restrict__ idx2,
                           const float* __restrict__ g1n, const float* __restrict__ g2n,
                           float* __restrict__ g1k, float* __restrict__ g2k,
                           int* __restrict__ pos1, int* __restrict__ pos2,
                           int* __restrict__ tokslot) {
    int th = blockIdx.x * blockDim.x + threadIdx.x;
    if (th >= BB*EE) return;
    int b = th >> 4, e = th & 15;
    int base = b * NN;
    int c1 = 0;
    for (int n = 0; n < NN; ++n) {
        int t = base + n;
        if (idx1[t] == e) {
            if (c1 < CAPX) {
                g1k[t] = g1n[t]; pos1[t] = c1;
                tokslot[(e*BB + b)*CAPX + c1] = t;
            } else { g1k[t] = 0.f; pos1[t] = 0; }
            c1++;
        }
    }
    int m1c = c1 < CAPX ? c1 : CAPX;
    int c2 = 0;
    for (int n = 0; n < NN; ++n) {
        int t = base + n;
        if (idx2[t] == e) {
            int p = c2 + m1c;
            if (p < CAPX) {
                g2k[t] = g2n[t]; pos2[t] = p;
                tokslot[(e*BB + b)*CAPX + p] = t;
            } else { g2k[t] = 0.f; pos2[t] = 0; }
            c2++;
        }
    }
}

// ---- Gather tokens into expert slots (zero-fill empty slots) ----
__global__ __launch_bounds__(256) void gather_k(const float* __restrict__ x,
                                                const int* __restrict__ tokslot,
                                                __hip_bfloat16* __restrict__ xin) {
    int sid = blockIdx.x;
    int t = tokslot[sid];
    __hip_bfloat16* op = xin + (size_t)sid * DD;
    if (t >= 0) {
        const float* xp = x + (size_t)t * DD;
        for (int d = threadIdx.x; d < DD; d += 256) op[d] = f2b(xp[d]);
    } else {
        for (int d = threadIdx.x; d < DD; d += 256) op[d] = f2b(0.f);
    }
}

// ---- Final combine: out(fp32) = h + g1*xo[e1,slot1] + g2*xo[e2,slot2] ----
__global__ __launch_bounds__(256) void combine_k(const float* __restrict__ h,
                                                 const __hip_bfloat16* __restrict__ xo,
                                                 const int* __restrict__ idx1, const int* __restrict__ idx2,
                                                 const int* __restrict__ pos1, const int* __restrict__ pos2,
                                                 const float* __restrict__ g1k, const float* __restrict__ g2k,
                                                 float* __restrict__ out) {
    int t = blockIdx.x;
    int b = t >> 10;
    float ga = g1k[t], gb = g2k[t];
    const __hip_bfloat16* xa = nullptr;
    const __hip_bfloat16* xb = nullptr;
    if (ga > 0.f) xa = xo + (size_t)((idx1[t]*BB + b)*CAPX + pos1[t]) * DD;
    if (gb > 0.f) xb = xo + (size_t)((idx2[t]*BB + b)*CAPX + pos2[t]) * DD;
    const float* hp = h + (size_t)t * DD;
    float* op = out + (size_t)t * DD;
    for (int d = threadIdx.x; d < DD; d += 256) {
        float v = hp[d];
        if (xa) v += ga * b2f(xa[d]);
        if (xb) v += gb * b2f(xb[d]);
        op[d] = v;
    }
}

// ---- Aux loss: mean(proxy*density)*E*E*coef -> fp32 scalar ----
__global__ void loss_k(const float* __restrict__ proxy, const float* __restrict__ cnt1,
                       float* __restrict__ out_loss) {
    int tid = threadIdx.x; // 128 threads, one per (b,e)
    float v = proxy[tid] * cnt1[tid];
#pragma unroll
    for (int off = 1; off < 64; off <<= 1) v += __shfl_xor(v, off);
    __shared__ float sm[2];
    if ((tid & 63) == 0) sm[tid >> 6] = v;
    __syncthreads();
    if (tid == 0) {
        float tot = sm[0] + sm[1];
        // loss = [sum_{b,e} (proxy/N)*(cnt/N)] / (B*E) * E*E * 0.01
        float loss = tot * (0.02f / (1024.f * 1024.f));
        *out_loss = loss;
    }
}

extern "C" void kernel_launch(void* const* d_in, const int* in_sizes, int n_in,
                              void* d_out, int out_size, void* d_ws, size_t ws_size,
                              hipStream_t stream) {
    // Inputs are float32 (reference dtype); OUTPUT is float32 (reference output dtype).
    const float* hid = (const float*)d_in[0];
    // d_in[1] = attention_mask (all-true) -> bias 0 -> unused
    const float* ln0 = (const float*)d_in[2];
    const float* Wq  = (const float*)d_in[3];
    const float* Wk  = (const float*)d_in[4];
    const float* Wv  = (const float*)d_in[5];
    const float* Wo  = (const float*)d_in[6];
    const float* ln1 = (const float*)d_in[7];
    const float* gw  = (const float*)d_in[8];
    const float* w1  = (const float*)d_in[9];
    const float* w2  = (const float*)d_in[10];
    float* out = (float*)d_out;

    // ---- Workspace with static liveness-based overlap (total ~176.5 MB) ----
    // SZ = one fp32 token-buffer = NT*DD*4 = 25,165,824 B (256-aligned)
    //   bufA: normed -> ctxf -> wT(lo)      (w1t/w2t bf16, 8 experts = 37.7 MB)
    //   bufB: qf            -> wT(hi)
    //   bufC: kf            -> hffn(lo)     (8-expert group, bf16 = 50.3 MB = C+D)
    //   bufD: vf            -> hffn(hi)
    //   hres: live to the end
    //   bufF: normed2 -> xo (bf16)
    const size_t SZ = (size_t)NT * DD * 4;
    char* p = (char*)d_ws;
    auto alloc = [&](size_t bytes) { char* r = p; p += (bytes + 255) & ~(size_t)255; return (void*)r; };
    float* bufA = (float*)alloc(SZ);
    float* bufB = (float*)alloc(SZ);
    float* bufC = (float*)alloc(SZ);
    float* bufD = (float*)alloc(SZ);
    float* hres = (float*)alloc(SZ);
    float* bufF = (float*)alloc(SZ);
    __hip_bfloat16* xin = (__hip_bfloat16*)alloc((size_t)EE*BB*CAPX*DD*2);
    int*   idx1 = (int*)alloc(NT*4);
    int*   idx2 = (int*)alloc(NT*4);
    float* g1n  = (float*)alloc(NT*4);
    float* g2n  = (float*)alloc(NT*4);
    float* g1k  = (float*)alloc(NT*4);
    float* g2k  = (float*)alloc(NT*4);
    int*   pos1 = (int*)alloc(NT*4);
    int*   pos2 = (int*)alloc(NT*4);
    int*   tokslot = (int*)alloc(EE*BB*CAPX*4);
    float* proxy   = (float*)alloc(BB*EE*4);
    float* cnt1f   = (float*)alloc(BB*EE*4);
    size_t needed = (size_t)(p - (char*)d_ws);
    if (needed > ws_size) return;  // out stays 0 -> absmax ~5.69 means "ws too small"

    float* normed  = bufA;
    float* qf      = bufB;
    float* kf      = bufC;
    float* vf      = bufD;
    float* ctxf    = bufA;                        // reuse: normed dead after QKV
    float* normed2 = bufF;
    __hip_bfloat16* wT   = (__hip_bfloat16*)bufA; // reuse: spans bufA+bufB (50.3 MB >= 37.7 MB)
    __hip_bfloat16* hffn = (__hip_bfloat16*)bufC; // reuse: spans bufC+bufD = 8-expert group exactly
    __hip_bfloat16* xo   = (__hip_bfloat16*)bufF; // reuse: normed2 dead after gather

    (void)hipMemsetAsync(tokslot, 0xFF, EE*BB*CAPX*4, stream);
    (void)hipMemsetAsync(proxy, 0, BB*EE*4, stream);
    (void)hipMemsetAsync(cnt1f, 0, BB*EE*4, stream);

    // 1. RMSNorm(hidden)
    rmsnorm_k<float><<<NT, 256, 0, stream>>>(hid, ln0, normed);
    // 2. Q,K,V projections (all fp32: routing must match reference argmax)
    dim3 gqkv(DD/128, NT/128, 1);
    gemm_k<float,float,float,false,false><<<gqkv, 256, 0, stream>>>(normed, Wq, qf, nullptr, NT, DD, DD, 0,0,0);
    gemm_k<float,float,float,false,false><<<gqkv, 256, 0, stream>>>(normed, Wk, kf, nullptr, NT, DD, DD, 0,0,0);
    gemm_k<float,float,float,false,false><<<gqkv, 256, 0, stream>>>(normed, Wv, vf, nullptr, NT, DD, DD, 0,0,0);
    // 3. Attention (unscaled, full softmax); writes ctxf (= bufA, normed now dead)
    attn_k<<<BB*HH*(NN/4), 256, 0, stream>>>(qf, kf, vf, ctxf);
    // 4. O-projection + residual -> h (fp32)
    gemm_k<float,float,float,false,true><<<gqkv, 256, 0, stream>>>(ctxf, Wo, hres, hid, NT, DD, DD, 0,0,0);
    // 5. RMSNorm(h)
    rmsnorm_k<float><<<NT, 256, 0, stream>>>(hres, ln1, normed2);
    // 6. Gating
    gate_k<<<NT/256, 256, 0, stream>>>(normed2, gw, idx1, idx2, g1n, g2n, proxy, cnt1f);
    // 7. Capacity assignment (sequential per (b,e))
    capacity_k<<<2, 64, 0, stream>>>(idx1, idx2, g1n, g2n, g1k, g2k, pos1, pos2, tokslot);
    // 8. Gather into expert slots (fp32 -> bf16)
    gather_k<<<EE*BB*CAPX, 256, 0, stream>>>(normed2, tokslot, xin);
    // 9/10. Expert FFN via bf16 MFMA, 2 groups of 8 experts (wT/hffn buffer reuse).
    //   Per group: w1^T -> wT; hffn = relu(xin @ w1); w2^T -> wT; xo = hffn @ w2.
    for (int g = 0; g < 2; ++g) {
        const int e0 = g * 8;
        // w1[e0..e0+7]: [DD][DFF] fp32 -> wT [DFF][DD] bf16
        transpose_cvt_k<<<dim3(DFF/32, DD/32, 8), 256, 0, stream>>>(
            w1 + (size_t)e0*DD*DFF, wT, DD, DFF);
        gemm_mfma_k<true><<<dim3(DFF/128, (BB*CAPX)/128, 8), 256, 0, stream>>>(
            xin + (size_t)e0*BB*CAPX*DD, wT, hffn,
            BB*CAPX, DFF, DD,
            (long)BB*CAPX*DD, (long)DD*DFF, (long)BB*CAPX*DFF);
        // w2[e0..e0+7]: [DFF][DD] fp32 -> wT [DD][DFF] bf16
        transpose_cvt_k<<<dim3(DD/32, DFF/32, 8), 256, 0, stream>>>(
            w2 + (size_t)e0*DFF*DD, wT, DFF, DD);
        gemm_mfma_k<false><<<dim3(DD/128, (BB*CAPX)/128, 8), 256, 0, stream>>>(
            hffn, wT, xo + (size_t)e0*BB*CAPX*DD,
            BB*CAPX, DD, DFF,
            (long)BB*CAPX*DFF, (long)DFF*DD, (long)BB*CAPX*DD);
    }
    // 11. Combine + residual -> output (fp32)
    combine_k<<<NT, 256, 0, stream>>>(hres, xo, idx1, idx2, pos1, pos2, g1k, g2k, out);
    // 12. Aux loss scalar (fp32)
    loss_k<<<1, 128, 0, stream>>>(proxy, cnt1f, out + (size_t)NT*DD);
}

// Round 2
// 2454.093 us; speedup vs baseline: 2.1996x; 2.1996x over previous
//
#include <hip/hip_runtime.h>
#include <hip/hip_bf16.h>

#define BB 8
#define NN 1024
#define DD 768
#define HH 12
#define DKVX 64
#define DFF 3072
#define EE 16
#define CAPX 128
#define NT (BB*NN)   // 8192 tokens

typedef __attribute__((ext_vector_type(8))) short bf16x8;
typedef __attribute__((ext_vector_type(4))) float f32x4;

__device__ __forceinline__ float b2f(__hip_bfloat16 x) { return __bfloat162float(x); }
__device__ __forceinline__ __hip_bfloat16 f2b(float x) { return __float2bfloat16(x); }
__device__ __forceinline__ float toFloat(float x) { return x; }
__device__ __forceinline__ float toFloat(__hip_bfloat16 x) { return __bfloat162float(x); }

// bf16 bit helpers for exact hi/lo splitting (x == hi + lo to ~2^-18 rel)
__device__ __forceinline__ unsigned short f2bu(float x) {
    __hip_bfloat16 h = __float2bfloat16(x);
    return *reinterpret_cast<unsigned short*>(&h);
}
__device__ __forceinline__ float bu2f(unsigned short u) {
    return __uint_as_float(((unsigned int)u) << 16);
}

// ---- 8-element vector loads (16B for bf16, 32B for float) ----
__device__ __forceinline__ void load8(const __hip_bfloat16* p, float* dst) {
    uint4 u = *reinterpret_cast<const uint4*>(p);
    const __hip_bfloat16* hb = reinterpret_cast<const __hip_bfloat16*>(&u);
#pragma unroll
    for (int i = 0; i < 8; ++i) dst[i] = b2f(hb[i]);
}
__device__ __forceinline__ void load8(const float* p, float* dst) {
    float4 a = reinterpret_cast<const float4*>(p)[0];
    float4 b = reinterpret_cast<const float4*>(p)[1];
    dst[0]=a.x; dst[1]=a.y; dst[2]=a.z; dst[3]=a.w;
    dst[4]=b.x; dst[5]=b.y; dst[6]=b.z; dst[7]=b.w;
}
__device__ __forceinline__ void storeC(float* p, float v) { *p = v; }
__device__ __forceinline__ void storeC(__hip_bfloat16* p, float v) { *p = f2b(v); }

// ---- RMSNorm (T5): out fp32 = x * rsqrt(mean(x^2)+1e-6) * w ----
template<typename TIN>
__global__ __launch_bounds__(256) void rmsnorm_k(const TIN* __restrict__ x,
                                                 const float* __restrict__ w,
                                                 float* __restrict__ out) {
    int t = blockIdx.x;
    int tid = threadIdx.x;
    const TIN* xp = x + (size_t)t * DD;
    float xv[3];
    float s = 0.f;
#pragma unroll
    for (int i = 0; i < 3; ++i) {
        float v = toFloat(xp[tid + i*256]);
        xv[i] = v; s += v*v;
    }
#pragma unroll
    for (int off = 1; off < 64; off <<= 1) s += __shfl_xor(s, off);
    __shared__ float sm[8];
    int wv = tid >> 6, ln = tid & 63;
    if (ln == 0) sm[wv] = s;
    __syncthreads();
    if (tid == 0) {
        float tot = sm[0]+sm[1]+sm[2]+sm[3];
        sm[4] = 1.0f / sqrtf(tot / (float)DD + 1e-6f);
    }
    __syncthreads();
    float sc = sm[4];
    float* op = out + (size_t)t * DD;
#pragma unroll
    for (int i = 0; i < 3; ++i) {
        int d = tid + i*256;
        op[d] = xv[i] * sc * w[d];
    }
}

// ---- Generic tiled GEMM (fp32 VALU path for the routing-critical projections):
// C[M,N] = A[M,K] @ B[K,N]; fp32 accum. 128x128 tile, BK=16, 256 threads, 8x8/thread.
template<typename TA, typename TB, typename TC, bool RELU, bool RESID>
__global__ __launch_bounds__(256) void gemm_k(const TA* __restrict__ A,
                                              const TB* __restrict__ B,
                                              TC* __restrict__ C,
                                              const float* __restrict__ R,
                                              int M, int N, int K,
                                              long sA, long sB, long sC) {
    __shared__ float As[16][132];
    __shared__ float Bs[16][132];
    const int bz = blockIdx.z;
    A += (size_t)bz * sA; B += (size_t)bz * sB; C += (size_t)bz * sC;
    const int row0 = blockIdx.y * 128, col0 = blockIdx.x * 128;
    const int tid = threadIdx.x;
    const int tx = tid & 15, ty = tid >> 4;
    const int ar = tid >> 1, ak = (tid & 1) * 8;   // A loader: row, k-offset
    const int bk = tid >> 4, bc = (tid & 15) * 8;  // B loader: k-row, col-offset
    float acc[8][8] = {};
    for (int k0 = 0; k0 < K; k0 += 16) {
        float av[8], bv[8];
        load8(A + (size_t)(row0 + ar) * K + (k0 + ak), av);
        load8(B + (size_t)(k0 + bk) * N + (col0 + bc), bv);
#pragma unroll
        for (int j = 0; j < 8; ++j) As[ak + j][ar] = av[j];
#pragma unroll
        for (int j = 0; j < 8; ++j) Bs[bk][bc + j] = bv[j];
        __syncthreads();
#pragma unroll
        for (int kk = 0; kk < 16; ++kk) {
            float a[8], b[8];
#pragma unroll
            for (int i = 0; i < 8; ++i) a[i] = As[kk][ty*8 + i];
#pragma unroll
            for (int j = 0; j < 8; ++j) b[j] = Bs[kk][tx*8 + j];
#pragma unroll
            for (int i = 0; i < 8; ++i)
#pragma unroll
                for (int j = 0; j < 8; ++j)
                    acc[i][j] += a[i] * b[j];
        }
        __syncthreads();
    }
#pragma unroll
    for (int i = 0; i < 8; ++i) {
        int r = row0 + ty*8 + i;
#pragma unroll
        for (int j = 0; j < 8; ++j) {
            int c = col0 + tx*8 + j;
            float v = acc[i][j];
            if (RESID) v += R[(size_t)r * N + c];
            if (RELU)  v = fmaxf(v, 0.f);
            storeC(C + (size_t)r * N + c, v);
        }
    }
}

// ---- Transpose + fp32->bf16 convert: in [K][N] fp32 -> out [N][K] bf16, batched z ----
__global__ __launch_bounds__(256) void transpose_cvt_k(const float* __restrict__ in,
                                                       __hip_bfloat16* __restrict__ outT,
                                                       int K, int N) {
    __shared__ float tile[32][33];
    const int z = blockIdx.z;
    in   += (size_t)z * K * N;
    outT += (size_t)z * K * N;
    const int n0 = blockIdx.x * 32, k0 = blockIdx.y * 32;
    const int tx = threadIdx.x & 31, ty = threadIdx.x >> 5;  // 32x8
#pragma unroll
    for (int i = 0; i < 4; ++i)
        tile[ty + 8*i][tx] = in[(size_t)(k0 + ty + 8*i) * N + n0 + tx];
    __syncthreads();
#pragma unroll
    for (int i = 0; i < 4; ++i)
        outT[(size_t)(n0 + ty + 8*i) * K + k0 + tx] = f2b(tile[tx][ty + 8*i]);
}

// ---- MFMA bf16 GEMM (FFN path): C[M,N](bf16) = A[M,K](bf16) @ Bt[N,K](bf16)^T.
template<bool RELU>
__global__ __launch_bounds__(256) void gemm_mfma_k(const __hip_bfloat16* __restrict__ A,
                                                   const __hip_bfloat16* __restrict__ Bt,
                                                   __hip_bfloat16* __restrict__ C,
                                                   int M, int N, int K,
                                                   long sA, long sB, long sC) {
    __shared__ unsigned short As[128][40];
    __shared__ unsigned short Bs[128][40];
    const int z = blockIdx.z;
    A  += (size_t)z * sA;
    Bt += (size_t)z * sB;
    C  += (size_t)z * sC;
    const int row0 = blockIdx.y * 128, col0 = blockIdx.x * 128;
    const int tid = threadIdx.x;
    const int lane = tid & 63, wid = tid >> 6;
    const int wr = (wid >> 1) * 64, wc = (wid & 1) * 64;
    const int lr = lane & 15, lkg = lane >> 4;
    const int srow = tid >> 1, skh = (tid & 1) * 16;

    const __hip_bfloat16* Ag = A  + (size_t)(row0 + srow) * K + skh;
    const __hip_bfloat16* Bg = Bt + (size_t)(col0 + srow) * K + skh;

    f32x4 acc[4][4] = {};
    uint4 a0 = *(const uint4*)(Ag);
    uint4 a1 = *(const uint4*)(Ag + 8);
    uint4 b0 = *(const uint4*)(Bg);
    uint4 b1 = *(const uint4*)(Bg + 8);
    for (int k0 = 0; k0 < K; k0 += 32) {
        __syncthreads();
        *(uint4*)&As[srow][skh]     = a0;
        *(uint4*)&As[srow][skh + 8] = a1;
        *(uint4*)&Bs[srow][skh]     = b0;
        *(uint4*)&Bs[srow][skh + 8] = b1;
        __syncthreads();
        if (k0 + 32 < K) {
            a0 = *(const uint4*)(Ag + k0 + 32);
            a1 = *(const uint4*)(Ag + k0 + 40);
            b0 = *(const uint4*)(Bg + k0 + 32);
            b1 = *(const uint4*)(Bg + k0 + 40);
        }
        bf16x8 af[4], bfr[4];
#pragma unroll
        for (int m = 0; m < 4; ++m)
            af[m] = *(const bf16x8*)&As[wr + m*16 + lr][lkg*8];
#pragma unroll
        for (int n = 0; n < 4; ++n)
            bfr[n] = *(const bf16x8*)&Bs[wc + n*16 + lr][lkg*8];
#pragma unroll
        for (int m = 0; m < 4; ++m)
#pragma unroll
            for (int n = 0; n < 4; ++n)
                acc[m][n] = __builtin_amdgcn_mfma_f32_16x16x32_bf16(af[m], bfr[n], acc[m][n], 0, 0, 0);
    }
#pragma unroll
    for (int m = 0; m < 4; ++m) {
#pragma unroll
        for (int n = 0; n < 4; ++n) {
#pragma unroll
            for (int r = 0; r < 4; ++r) {
                int rr = row0 + wr + m*16 + lkg*4 + r;
                int cc = col0 + wc + n*16 + lr;
                float v = acc[m][n][r];
                if (RELU) v = fmaxf(v, 0.f);
                C[(size_t)rr * N + cc] = f2b(v);
            }
        }
    }
}

// ==================== split-bf16 MFMA attention ====================
// Exact compensation: x = hi + lo (bf16 each), S = (Qhi+Qlo)(Khi+Klo) as 4 MFMA terms.
// Packs store [hi | lo] (128 cols); the QK kernel maps effective k in [0,256):
//   A col = k & 127                        (pattern: Qhi,Qlo,Qhi,Qlo)
//   B col = ((k>>7)<<6) | (k&63)           (pattern: Khi,Khi,Klo,Klo)
// so sum = Qhi.Khi + Qlo.Khi + Qhi.Klo + Qlo.Klo.

// Pack Q,K rows: per head write [Qhi(64)|Qlo(64)] into head-major [bh][n][128].
__global__ __launch_bounds__(256) void pack_qk_k(const float* __restrict__ qf,
                                                 const float* __restrict__ kf,
                                                 __hip_bfloat16* __restrict__ Aq,
                                                 __hip_bfloat16* __restrict__ Bk) {
    const int t = blockIdx.x * 16 + (threadIdx.x >> 4);
    const int quad = threadIdx.x & 15;
    const int b = t >> 10, n = t & 1023;
    const float* qp = qf + (size_t)t * DD;
    const float* kp = kf + (size_t)t * DD;
#pragma unroll
    for (int h = 0; h < HH; ++h) {
        float4 qv = *(const float4*)(qp + h*64 + quad*4);
        float4 kv = *(const float4*)(kp + h*64 + quad*4);
        size_t rowbase = ((size_t)(b*HH + h) * NN + n) * 128;
        float qa[4] = {qv.x,qv.y,qv.z,qv.w};
        float ka[4] = {kv.x,kv.y,kv.z,kv.w};
        unsigned short qh[4], ql[4], kh[4], kl[4];
#pragma unroll
        for (int j = 0; j < 4; ++j) {
            unsigned short hb = f2bu(qa[j]); qh[j]=hb; ql[j]=f2bu(qa[j]-bu2f(hb));
            unsigned short hc = f2bu(ka[j]); kh[j]=hc; kl[j]=f2bu(ka[j]-bu2f(hc));
        }
        unsigned short* aq = (unsigned short*)Aq + rowbase + quad*4;
        unsigned short* bk = (unsigned short*)Bk + rowbase + quad*4;
        *(uint2*)aq        = *(uint2*)qh;
        *(uint2*)(aq + 64) = *(uint2*)ql;
        *(uint2*)bk        = *(uint2*)kh;
        *(uint2*)(bk + 64) = *(uint2*)kl;
    }
}

// Pack V transposed: Vt[bh][d][0..1023]=Vhi^T, [d][1024..2047]=Vlo^T.
__global__ __launch_bounds__(256) void pack_v_k(const float* __restrict__ vf,
                                                __hip_bfloat16* __restrict__ Vt) {
    __shared__ float tile[32][65];
    const int bh = blockIdx.y, nt = blockIdx.x;
    const int b = bh / HH, h = bh % HH;
    const int n0 = nt * 32;
    const int tid = threadIdx.x;
    {
        int nr = tid >> 3, ds = (tid & 7) * 8;
        const float* vp = vf + ((size_t)(b*NN + n0 + nr) * DD) + h*64 + ds;
        float4 v0 = *(const float4*)vp;
        float4 v1 = *(const float4*)(vp + 4);
        tile[nr][ds+0]=v0.x; tile[nr][ds+1]=v0.y; tile[nr][ds+2]=v0.z; tile[nr][ds+3]=v0.w;
        tile[nr][ds+4]=v1.x; tile[nr][ds+5]=v1.y; tile[nr][ds+6]=v1.z; tile[nr][ds+7]=v1.w;
    }
    __syncthreads();
    {
        int d = tid >> 2, ns = (tid & 3) * 8;
        unsigned short hs[8], ls[8];
#pragma unroll
        for (int j = 0; j < 8; ++j) {
            float x = tile[ns+j][d];
            unsigned short hb = f2bu(x);
            hs[j] = hb; ls[j] = f2bu(x - bu2f(hb));
        }
        unsigned short* dst = (unsigned short*)Vt + ((size_t)bh*64 + d)*2048 + n0 + ns;
        *(uint4*)dst          = *(uint4*)hs;
        *(uint4*)(dst + 1024) = *(uint4*)ls;
    }
}

// Scores: S[z][1024][1024] fp32 = (Qhi+Qlo).(Khi+Klo) via Keff=256 wrapped MFMA.
__global__ __launch_bounds__(256) void attn_qk_k(const __hip_bfloat16* __restrict__ Aq,
                                                 const __hip_bfloat16* __restrict__ Bk,
                                                 float* __restrict__ S, int bh0) {
    __shared__ unsigned short As[128][40];
    __shared__ unsigned short Bs[128][40];
    const int z = blockIdx.z, bh = bh0 + z;
    const __hip_bfloat16* A  = Aq + (size_t)bh * NN * 128;
    const __hip_bfloat16* Bt = Bk + (size_t)bh * NN * 128;
    float* C = S + (size_t)z * NN * NN;
    const int row0 = blockIdx.y * 128, col0 = blockIdx.x * 128;
    const int tid = threadIdx.x;
    const int lane = tid & 63, wid = tid >> 6;
    const int wr = (wid >> 1) * 64, wc = (wid & 1) * 64;
    const int lr = lane & 15, lkg = lane >> 4;
    const int srow = tid >> 1, skh = (tid & 1) * 16;

    const __hip_bfloat16* Ag = A  + (size_t)(row0 + srow) * 128;
    const __hip_bfloat16* Bg = Bt + (size_t)(col0 + srow) * 128;

    f32x4 acc[4][4] = {};
    uint4 a0, a1, b0, b1;
    {
        int ka = skh & 127;
        a0 = *(const uint4*)(Ag + ka); a1 = *(const uint4*)(Ag + ka + 8);
        int kb = ((skh >> 7) << 6) | (skh & 63);
        b0 = *(const uint4*)(Bg + kb); b1 = *(const uint4*)(Bg + kb + 8);
    }
    for (int k0 = 0; k0 < 256; k0 += 32) {
        __syncthreads();
        *(uint4*)&As[srow][skh]     = a0;
        *(uint4*)&As[srow][skh + 8] = a1;
        *(uint4*)&Bs[srow][skh]     = b0;
        *(uint4*)&Bs[srow][skh + 8] = b1;
        __syncthreads();
        if (k0 + 32 < 256) {
            int kk = k0 + 32 + skh;
            int ka = kk & 127;
            a0 = *(const uint4*)(Ag + ka); a1 = *(const uint4*)(Ag + ka + 8);
            int kb = ((kk >> 7) << 6) | (kk & 63);
            b0 = *(const uint4*)(Bg + kb); b1 = *(const uint4*)(Bg + kb + 8);
        }
        bf16x8 af[4], bfr[4];
#pragma unroll
        for (int m = 0; m < 4; ++m)
            af[m] = *(const bf16x8*)&As[wr + m*16 + lr][lkg*8];
#pragma unroll
        for (int n = 0; n < 4; ++n)
            bfr[n] = *(const bf16x8*)&Bs[wc + n*16 + lr][lkg*8];
#pragma unroll
        for (int m = 0; m < 4; ++m)
#pragma unroll
            for (int n = 0; n < 4; ++n)
                acc[m][n] = __builtin_amdgcn_mfma_f32_16x16x32_bf16(af[m], bfr[n], acc[m][n], 0, 0, 0);
    }
#pragma unroll
    for (int m = 0; m < 4; ++m)
#pragma unroll
        for (int n = 0; n < 4; ++n)
#pragma unroll
            for (int r = 0; r < 4; ++r) {
                int rr = row0 + wr + m*16 + lkg*4 + r;
                int cc = col0 + wc + n*16 + lr;
                C[(size_t)rr * NN + cc] = acc[m][n][r];
            }
}

// Fused softmax + PV: per block = 64 query rows x full 64-dim output, one (b,h).
// Prologue: online max/sum-exp over the row's 1024 scores. Main loop per 32 keys:
// regenerate P=exp(s-m)*inv, split hi/lo into LDS, stage Vhi/Vlo tiles, and do
// 4-term MFMA (Phi+Plo)(Vhi+Vlo). ctx written fp32 strided into [t][768] layout.
__global__ __launch_bounds__(256) void attn_pv_k(const float* __restrict__ S,
                                                 const __hip_bfloat16* __restrict__ Vt,
                                                 float* __restrict__ ctx, int bh0) {
    __shared__ unsigned short Ahi[64][40], Alo[64][40];
    __shared__ unsigned short Bhi[64][40], Blo[64][40];
    __shared__ float mrow[64], irow[64];
    const int z = blockIdx.y, bh = bh0 + z;
    const int b = bh / HH, h = bh % HH;
    const int row0 = blockIdx.x * 64;
    const float* Sb = S + (size_t)z * NN * NN;
    const unsigned short* Vb = (const unsigned short*)Vt + (size_t)bh * 64 * 2048;
    const int tid = threadIdx.x, lane = tid & 63, wid = tid >> 6;
    const int lr = lane & 15, lkg = lane >> 4;

    // ---- stats: online max / sum-exp, 4 threads per row ----
    {
        int r = tid >> 2, seg = tid & 3;
        const float4* sp = (const float4*)(Sb + (size_t)(row0 + r) * NN + seg * 256);
        float m = -1e30f, sum = 0.f;
#pragma unroll 8
        for (int j = 0; j < 64; ++j) {
            float4 v = sp[j];
            float m4 = fmaxf(fmaxf(v.x, v.y), fmaxf(v.z, v.w));
            float mn = fmaxf(m, m4);
            sum = sum * __expf(m - mn)
                + __expf(v.x - mn) + __expf(v.y - mn)
                + __expf(v.z - mn) + __expf(v.w - mn);
            m = mn;
        }
        float mo = __shfl_xor(m, 1), so = __shfl_xor(sum, 1);
        float M = fmaxf(m, mo); sum = sum*__expf(m - M) + so*__expf(mo - M); m = M;
        mo = __shfl_xor(m, 2); so = __shfl_xor(sum, 2);
        M = fmaxf(m, mo); sum = sum*__expf(m - M) + so*__expf(mo - M); m = M;
        if (seg == 0) { mrow[r] = m; irow[r] = 1.0f / sum; }
    }
    __syncthreads();

    const int ar = tid >> 2, aks = (tid & 3) * 8;
    const float* Ap = Sb + (size_t)(row0 + ar) * NN + aks;
    const float mr = mrow[ar], ir = irow[ar];
    const int vd = tid >> 2, vg = tid & 3;
    const int vhalf = vg >> 1, vks = (vg & 1) * 16;
    const unsigned short* Vp = Vb + (size_t)vd * 2048 + vhalf * 1024 + vks;

    f32x4 acc[4] = {};
    float4 sa0 = *(const float4*)(Ap);
    float4 sa1 = *(const float4*)(Ap + 4);
    uint4 vb0 = *(const uint4*)(Vp);
    uint4 vb1 = *(const uint4*)(Vp + 8);
    for (int kc = 0; kc < NN; kc += 32) {
        __syncthreads();
        {   // A tiles: exp + hi/lo split
            float sv[8] = {sa0.x,sa0.y,sa0.z,sa0.w, sa1.x,sa1.y,sa1.z,sa1.w};
            unsigned short hs[8], ls[8];
#pragma unroll
            for (int j = 0; j < 8; ++j) {
                float p = __expf(sv[j] - mr) * ir;
                unsigned short hb = f2bu(p);
                hs[j] = hb; ls[j] = f2bu(p - bu2f(hb));
            }
            *(uint4*)&Ahi[ar][aks] = *(uint4*)hs;
            *(uint4*)&Alo[ar][aks] = *(uint4*)ls;
        }
        {   // B tiles: direct copy
            unsigned short* dh = vhalf ? &Blo[vd][vks] : &Bhi[vd][vks];
            *(uint4*)dh       = vb0;
            *(uint4*)(dh + 8) = vb1;
        }
        __syncthreads();
        if (kc + 32 < NN) {
            sa0 = *(const float4*)(Ap + kc + 32);
            sa1 = *(const float4*)(Ap + kc + 36);
            vb0 = *(const uint4*)(Vp + kc + 32);
            vb1 = *(const uint4*)(Vp + kc + 40);
        }
        bf16x8 ah = *(const bf16x8*)&Ahi[wid*16 + lr][lkg*8];
        bf16x8 al = *(const bf16x8*)&Alo[wid*16 + lr][lkg*8];
#pragma unroll
        for (int n = 0; n < 4; ++n) {
            bf16x8 bhv = *(const bf16x8*)&Bhi[n*16 + lr][lkg*8];
            bf16x8 blv = *(const bf16x8*)&Blo[n*16 + lr][lkg*8];
            acc[n] = __builtin_amdgcn_mfma_f32_16x16x32_bf16(ah, bhv, acc[n], 0, 0, 0);
            acc[n] = __builtin_amdgcn_mfma_f32_16x16x32_bf16(al, bhv, acc[n], 0, 0, 0);
            acc[n] = __builtin_amdgcn_mfma_f32_16x16x32_bf16(ah, blv, acc[n], 0, 0, 0);
            acc[n] = __builtin_amdgcn_mfma_f32_16x16x32_bf16(al, blv, acc[n], 0, 0, 0);
        }
    }
#pragma unroll
    for (int n = 0; n < 4; ++n)
#pragma unroll
        for (int r2 = 0; r2 < 4; ++r2) {
            int row = row0 + wid*16 + lkg*4 + r2;
            int col = n*16 + lr;
            ctx[((size_t)(b*NN + row) * DD) + h*64 + col] = acc[n][r2];
        }
}

// ---- Gate: logits -> softmax -> top2 (+normalized gates), proxy/density accum
__global__ __launch_bounds__(256) void gate_k(const float* __restrict__ x,
                                              const float* __restrict__ gw,
                                              int* __restrict__ idx1, int* __restrict__ idx2,
                                              float* __restrict__ g1n, float* __restrict__ g2n,
                                              float* __restrict__ proxy, float* __restrict__ cnt1) {
    __shared__ float gws[DD*EE];
    for (int i = threadIdx.x; i < DD*EE; i += 256) gws[i] = gw[i];
    __syncthreads();
    int t = blockIdx.x * 256 + threadIdx.x;
    int b = t >> 10;
    float acc[EE] = {};
    const float4* xp = (const float4*)(x + (size_t)t * DD);
    for (int d4 = 0; d4 < DD/4; ++d4) {
        float4 xv = xp[d4];
        float xs[4] = {xv.x, xv.y, xv.z, xv.w};
#pragma unroll
        for (int qq = 0; qq < 4; ++qq) {
            const float* g = &gws[(d4*4+qq)*EE];
#pragma unroll
            for (int e = 0; e < EE; ++e) acc[e] += xs[qq] * g[e];
        }
    }
    float m = acc[0];
#pragma unroll
    for (int e = 1; e < EE; ++e) m = fmaxf(m, acc[e]);
    float sum = 0.f;
    float raw[EE];
#pragma unroll
    for (int e = 0; e < EE; ++e) { raw[e] = expf(acc[e] - m); sum += raw[e]; }
    float inv = 1.0f / sum;
#pragma unroll
    for (int e = 0; e < EE; ++e) raw[e] *= inv;
    int i1 = 0; float p1 = raw[0];
#pragma unroll
    for (int e = 1; e < EE; ++e) if (raw[e] > p1) { p1 = raw[e]; i1 = e; }
    int i2 = (i1 == 0) ? 1 : 0; float p2 = raw[i2];
#pragma unroll
    for (int e = 0; e < EE; ++e) if (e != i1 && raw[e] > p2) { p2 = raw[e]; i2 = e; }
    float den = p1 + p2 + 1e-9f;
    idx1[t] = i1; idx2[t] = i2;
    g1n[t] = p1 / den; g2n[t] = p2 / den;
    int ln = threadIdx.x & 63;
#pragma unroll
    for (int e = 0; e < EE; ++e) {
        float r = raw[e];
#pragma unroll
        for (int off = 1; off < 64; off <<= 1) r += __shfl_xor(r, off);
        if (ln == 0) atomicAdd(&proxy[b*EE + e], r);
    }
#pragma unroll
    for (int e = 0; e < EE; ++e) {
        unsigned long long mb = __ballot(i1 == e);
        if (ln == 0 && mb) atomicAdd(&cnt1[b*EE + e], (float)__popcll(mb));
    }
}

// ---- Capacity: literal sequential scan per (b,e). 128 threads total.
__global__ void capacity_k(const int* __restrict__ idx1, const int* __restrict__ idx2,
                           const float* __restrict__ g1n, const float* __restrict__ g2n,
                           float* __restrict__ g1k, float* __restrict__ g2k,
                           int* __restrict__ pos1, int* __restrict__ pos2,
                           int* __restrict__ tokslot) {
    int th = blockIdx.x * blockDim.x + threadIdx.x;
    if (th >= BB*EE) return;
    int b = th >> 4, e = th & 15;
    int base = b * NN;
    int c1 = 0;
    for (int n = 0; n < NN; ++n) {
        int t = base + n;
        if (idx1[t] == e) {
            if (c1 < CAPX) {
                g1k[t] = g1n[t]; pos1[t] = c1;
                tokslot[(e*BB + b)*CAPX + c1] = t;
            } else { g1k[t] = 0.f; pos1[t] = 0; }
            c1++;
        }
    }
    int m1c = c1 < CAPX ? c1 : CAPX;
    int c2 = 0;
    for (int n = 0; n < NN; ++n) {
        int t = base + n;
        if (idx2[t] == e) {
            int p = c2 + m1c;
            if (p < CAPX) {
                g2k[t] = g2n[t]; pos2[t] = p;
                tokslot[(e*BB + b)*CAPX + p] = t;
            } else { g2k[t] = 0.f; pos2[t] = 0; }
            c2++;
        }
    }
}

// ---- Gather tokens into expert slots (zero-fill empty slots) ----
__global__ __launch_bounds__(256) void gather_k(const float* __restrict__ x,
                                                const int* __restrict__ tokslot,
                                                __hip_bfloat16* __restrict__ xin) {
    int sid = blockIdx.x;
    int t = tokslot[sid];
    __hip_bfloat16* op = xin + (size_t)sid * DD;
    if (t >= 0) {
        const float* xp = x + (size_t)t * DD;
        for (int d = threadIdx.x; d < DD; d += 256) op[d] = f2b(xp[d]);
    } else {
        for (int d = threadIdx.x; d < DD; d += 256) op[d] = f2b(0.f);
    }
}

// ---- Final combine: out(fp32) = h + g1*xo[e1,slot1] + g2*xo[e2,slot2] ----
__global__ __launch_bounds__(256) void combine_k(const float* __restrict__ h,
                                                 const __hip_bfloat16* __restrict__ xo,
                                                 const int* __restrict__ idx1, const int* __restrict__ idx2,
                                                 const int* __restrict__ pos1, const int* __restrict__ pos2,
                                                 const float* __restrict__ g1k, const float* __restrict__ g2k,
                                                 float* __restrict__ out) {
    int t = blockIdx.x;
    int b = t >> 10;
    float ga = g1k[t], gb = g2k[t];
    const __hip_bfloat16* xa = nullptr;
    const __hip_bfloat16* xb = nullptr;
    if (ga > 0.f) xa = xo + (size_t)((idx1[t]*BB + b)*CAPX + pos1[t]) * DD;
    if (gb > 0.f) xb = xo + (size_t)((idx2[t]*BB + b)*CAPX + pos2[t]) * DD;
    const float* hp = h + (size_t)t * DD;
    float* op = out + (size_t)t * DD;
    for (int d = threadIdx.x; d < DD; d += 256) {
        float v = hp[d];
        if (xa) v += ga * b2f(xa[d]);
        if (xb) v += gb * b2f(xb[d]);
        op[d] = v;
    }
}

// ---- Aux loss: mean(proxy*density)*E*E*coef -> fp32 scalar ----
__global__ void loss_k(const float* __restrict__ proxy, const float* __restrict__ cnt1,
                       float* __restrict__ out_loss) {
    int tid = threadIdx.x; // 128 threads, one per (b,e)
    float v = proxy[tid] * cnt1[tid];
#pragma unroll
    for (int off = 1; off < 64; off <<= 1) v += __shfl_xor(v, off);
    __shared__ float sm[2];
    if ((tid & 63) == 0) sm[tid >> 6] = v;
    __syncthreads();
    if (tid == 0) {
        float tot = sm[0] + sm[1];
        float loss = tot * (0.02f / (1024.f * 1024.f));
        *out_loss = loss;
    }
}

extern "C" void kernel_launch(void* const* d_in, const int* in_sizes, int n_in,
                              void* d_out, int out_size, void* d_ws, size_t ws_size,
                              hipStream_t stream) {
    const float* hid = (const float*)d_in[0];
    const float* ln0 = (const float*)d_in[2];
    const float* Wq  = (const float*)d_in[3];
    const float* Wk  = (const float*)d_in[4];
    const float* Wv  = (const float*)d_in[5];
    const float* Wo  = (const float*)d_in[6];
    const float* ln1 = (const float*)d_in[7];
    const float* gw  = (const float*)d_in[8];
    const float* w1  = (const float*)d_in[9];
    const float* w2  = (const float*)d_in[10];
    float* out = (float*)d_out;

    // ---- Workspace (unchanged total ~176.5 MB), SZ = NT*DD*4 = 25,165,824 B ----
    //   bufA: normed -> Aq2(bf16)         -> wT(lo)
    //   bufB: qf     -> S_c lo half       -> wT(hi)
    //   bufC: kf     -> S_c hi half       -> hffn(lo)
    //   bufD: vf     -> ctxf              -> hffn(hi)
    //   hres: Bk2(bf16) -> h (live to end)
    //   bufF: Vt2(bf16) -> normed2 -> xo(bf16)
    const size_t SZ = (size_t)NT * DD * 4;
    char* p = (char*)d_ws;
    auto alloc = [&](size_t bytes) { char* r = p; p += (bytes + 255) & ~(size_t)255; return (void*)r; };
    float* bufA = (float*)alloc(SZ);
    float* bufB = (float*)alloc(SZ);
    float* bufC = (float*)alloc(SZ);
    float* bufD = (float*)alloc(SZ);
    float* hres = (float*)alloc(SZ);
    float* bufF = (float*)alloc(SZ);
    __hip_bfloat16* xin = (__hip_bfloat16*)alloc((size_t)EE*BB*CAPX*DD*2);
    int*   idx1 = (int*)alloc(NT*4);
    int*   idx2 = (int*)alloc(NT*4);
    float* g1n  = (float*)alloc(NT*4);
    float* g2n  = (float*)alloc(NT*4);
    float* g1k  = (float*)alloc(NT*4);
    float* g2k  = (float*)alloc(NT*4);
    int*   pos1 = (int*)alloc(NT*4);
    int*   pos2 = (int*)alloc(NT*4);
    int*   tokslot = (int*)alloc(EE*BB*CAPX*4);
    float* proxy   = (float*)alloc(BB*EE*4);
    float* cnt1f   = (float*)alloc(BB*EE*4);
    size_t needed = (size_t)(p - (char*)d_ws);
    if (needed > ws_size) return;

    float* normed  = bufA;
    float* qf      = bufB;
    float* kf      = bufC;
    float* vf      = bufD;
    __hip_bfloat16* Aq2 = (__hip_bfloat16*)bufA;  // 96*1024*128 bf16 = SZ exactly
    __hip_bfloat16* Bk2 = (__hip_bfloat16*)hres;  // hres written later (after attention)
    __hip_bfloat16* Vt2 = (__hip_bfloat16*)bufF;  // 96*64*2048 bf16 = SZ exactly
    float* S_c     = bufB;                        // 12 heads * 1024*1024 fp32 = 2*SZ (B+C)
    float* ctxf    = bufD;                        // vf dead after pack_v
    float* normed2 = bufF;                        // Vt2 dead after attention
    __hip_bfloat16* wT   = (__hip_bfloat16*)bufA; // FFN: spans bufA+bufB
    __hip_bfloat16* hffn = (__hip_bfloat16*)bufC; // FFN: spans bufC+bufD
    __hip_bfloat16* xo   = (__hip_bfloat16*)bufF;

    (void)hipMemsetAsync(tokslot, 0xFF, EE*BB*CAPX*4, stream);
    (void)hipMemsetAsync(proxy, 0, BB*EE*4, stream);
    (void)hipMemsetAsync(cnt1f, 0, BB*EE*4, stream);

    // 1. RMSNorm(hidden)
    rmsnorm_k<float><<<NT, 256, 0, stream>>>(hid, ln0, normed);
    // 2. Q,K,V projections (fp32 VALU: routing must match reference argmax)
    dim3 gqkv(DD/128, NT/128, 1);
    gemm_k<float,float,float,false,false><<<gqkv, 256, 0, stream>>>(normed, Wq, qf, nullptr, NT, DD, DD, 0,0,0);
    gemm_k<float,float,float,false,false><<<gqkv, 256, 0, stream>>>(normed, Wk, kf, nullptr, NT, DD, DD, 0,0,0);
    gemm_k<float,float,float,false,false><<<gqkv, 256, 0, stream>>>(normed, Wv, vf, nullptr, NT, DD, DD, 0,0,0);
    // 3. Attention via exact split-bf16 MFMA (4-term compensation, ~fp32 accurate)
    pack_qk_k<<<NT/16, 256, 0, stream>>>(qf, kf, Aq2, Bk2);
    pack_v_k<<<dim3(NN/32, BB*HH), 256, 0, stream>>>(vf, Vt2);
    for (int c = 0; c < 8; ++c) {
        int bh0 = c * HH;  // chunk of 12 (b,h) pairs; S_c reused per chunk
        attn_qk_k<<<dim3(NN/128, NN/128, HH), 256, 0, stream>>>(Aq2, Bk2, S_c, bh0);
        attn_pv_k<<<dim3(NN/64, HH), 256, 0, stream>>>(S_c, Vt2, ctxf, bh0);
    }
    // 4. O-projection + residual -> h (fp32)
    gemm_k<float,float,float,false,true><<<gqkv, 256, 0, stream>>>(ctxf, Wo, hres, hid, NT, DD, DD, 0,0,0);
    // 5. RMSNorm(h)
    rmsnorm_k<float><<<NT, 256, 0, stream>>>(hres, ln1, normed2);
    // 6. Gating
    gate_k<<<NT/256, 256, 0, stream>>>(normed2, gw, idx1, idx2, g1n, g2n, proxy, cnt1f);
    // 7. Capacity assignment (sequential per (b,e))
    capacity_k<<<2, 64, 0, stream>>>(idx1, idx2, g1n, g2n, g1k, g2k, pos1, pos2, tokslot);
    // 8. Gather into expert slots (fp32 -> bf16)
    gather_k<<<EE*BB*CAPX, 256, 0, stream>>>(normed2, tokslot, xin);
    // 9/10. Expert FFN via bf16 MFMA, 2 groups of 8 experts
    for (int g = 0; g < 2; ++g) {
        const int e0 = g * 8;
        transpose_cvt_k<<<dim3(DFF/32, DD/32, 8), 256, 0, stream>>>(
            w1 + (size_t)e0*DD*DFF, wT, DD, DFF);
        gemm_mfma_k<true><<<dim3(DFF/128, (BB*CAPX)/128, 8), 256, 0, stream>>>(
            xin + (size_t)e0*BB*CAPX*DD, wT, hffn,
            BB*CAPX, DFF, DD,
            (long)BB*CAPX*DD, (long)DD*DFF, (long)BB*CAPX*DFF);
        transpose_cvt_k<<<dim3(DD/32, DFF/32, 8), 256, 0, stream>>>(
            w2 + (size_t)e0*DFF*DD, wT, DFF, DD);
        gemm_mfma_k<false><<<dim3(DD/128, (BB*CAPX)/128, 8), 256, 0, stream>>>(
            hffn, wT, xo + (size_t)e0*BB*CAPX*DD,
            BB*CAPX, DD, DFF,
            (long)BB*CAPX*DFF, (long)DFF*DD, (long)BB*CAPX*DD);
    }
    // 11. Combine + residual -> output (fp32)
    combine_k<<<NT, 256, 0, stream>>>(hres, xo, idx1, idx2, pos1, pos2, g1k, g2k, out);
    // 12. Aux loss scalar (fp32)
    loss_k<<<1, 128, 0, stream>>>(proxy, cnt1f, out + (size_t)NT*DD);
}

// Round 3
// 1533.382 us; speedup vs baseline: 3.5203x; 1.6004x over previous
//
#include <hip/hip_runtime.h>
#include <hip/hip_bf16.h>

#define BB 8
#define NN 1024
#define DD 768
#define HH 12
#define DKVX 64
#define DFF 3072
#define EE 16
#define CAPX 128
#define NT (BB*NN)   // 8192 tokens

typedef __attribute__((ext_vector_type(8))) short bf16x8;
typedef __attribute__((ext_vector_type(4))) float f32x4;

__device__ __forceinline__ float b2f(__hip_bfloat16 x) { return __bfloat162float(x); }
__device__ __forceinline__ __hip_bfloat16 f2b(float x) { return __float2bfloat16(x); }
__device__ __forceinline__ float toFloat(float x) { return x; }
__device__ __forceinline__ float toFloat(__hip_bfloat16 x) { return __bfloat162float(x); }

// bf16 bit helpers for exact hi/lo splitting (x == hi + lo to ~2^-18 rel)
__device__ __forceinline__ unsigned short f2bu(float x) {
    __hip_bfloat16 h = __float2bfloat16(x);
    return *reinterpret_cast<unsigned short*>(&h);
}
__device__ __forceinline__ float bu2f(unsigned short u) {
    return __uint_as_float(((unsigned int)u) << 16);
}

// ---- RMSNorm (T5) fp32 out: out = x * rsqrt(mean(x^2)+1e-6) * w ----
template<typename TIN>
__global__ __launch_bounds__(256) void rmsnorm_k(const TIN* __restrict__ x,
                                                 const float* __restrict__ w,
                                                 float* __restrict__ out) {
    int t = blockIdx.x;
    int tid = threadIdx.x;
    const TIN* xp = x + (size_t)t * DD;
    float xv[3];
    float s = 0.f;
#pragma unroll
    for (int i = 0; i < 3; ++i) {
        float v = toFloat(xp[tid + i*256]);
        xv[i] = v; s += v*v;
    }
#pragma unroll
    for (int off = 1; off < 64; off <<= 1) s += __shfl_xor(s, off);
    __shared__ float sm[8];
    int wv = tid >> 6, ln = tid & 63;
    if (ln == 0) sm[wv] = s;
    __syncthreads();
    if (tid == 0) {
        float tot = sm[0]+sm[1]+sm[2]+sm[3];
        sm[4] = 1.0f / sqrtf(tot / (float)DD + 1e-6f);
    }
    __syncthreads();
    float sc = sm[4];
    float* op = out + (size_t)t * DD;
#pragma unroll
    for (int i = 0; i < 3; ++i) {
        int d = tid + i*256;
        op[d] = xv[i] * sc * w[d];
    }
}

// ---- RMSNorm fused with hi/lo split pack: out bf16 [t][1536] = [hi(768)|lo(768)] ----
__global__ __launch_bounds__(192) void rmsnorm_split_k(const float* __restrict__ x,
                                                       const float* __restrict__ w,
                                                       __hip_bfloat16* __restrict__ out) {
    int t = blockIdx.x, tid = threadIdx.x;
    float4 xv = *(const float4*)(x + (size_t)t * DD + tid * 4);
    float s = xv.x*xv.x + xv.y*xv.y + xv.z*xv.z + xv.w*xv.w;
#pragma unroll
    for (int off = 1; off < 64; off <<= 1) s += __shfl_xor(s, off);
    __shared__ float sm[4];
    int wv = tid >> 6, ln = tid & 63;
    if (ln == 0) sm[wv] = s;
    __syncthreads();
    if (tid == 0) sm[3] = 1.0f / sqrtf((sm[0]+sm[1]+sm[2]) / (float)DD + 1e-6f);
    __syncthreads();
    float sc = sm[3];
    float4 wv4 = *(const float4*)(w + tid * 4);
    float y[4] = {xv.x*sc*wv4.x, xv.y*sc*wv4.y, xv.z*sc*wv4.z, xv.w*sc*wv4.w};
    unsigned short hs[4], ls[4];
#pragma unroll
    for (int j = 0; j < 4; ++j) {
        hs[j] = f2bu(y[j]);
        ls[j] = f2bu(y[j] - bu2f(hs[j]));
    }
    unsigned short* op = (unsigned short*)out + (size_t)t * 1536 + tid * 4;
    *(uint2*)op         = *(uint2*)hs;
    *(uint2*)(op + 768) = *(uint2*)ls;
}

// ---- Weight transpose + hi/lo split: in [K=768][N=768] fp32 -> out [N][1536] bf16 ----
__global__ __launch_bounds__(256) void transpose_split_k(const float* __restrict__ in,
                                                         __hip_bfloat16* __restrict__ outT) {
    __shared__ float tile[32][33];
    const int n0 = blockIdx.x * 32, k0 = blockIdx.y * 32;
    const int tx = threadIdx.x & 31, ty = threadIdx.x >> 5;  // 32x8
#pragma unroll
    for (int i = 0; i < 4; ++i)
        tile[ty + 8*i][tx] = in[(size_t)(k0 + ty + 8*i) * DD + n0 + tx];
    __syncthreads();
#pragma unroll
    for (int i = 0; i < 4; ++i) {
        float x = tile[tx][ty + 8*i];
        unsigned short hb = f2bu(x);
        unsigned short lb = f2bu(x - bu2f(hb));
        unsigned short* op = (unsigned short*)outT + (size_t)(n0 + ty + 8*i) * 1536 + k0 + tx;
        op[0]   = hb;
        op[768] = lb;
    }
}

// ---- 4-term split-bf16 MFMA projection GEMM (~fp32 exact):
// C[NT][768] fp32 = A'[NT][1536] x Bt'[768][1536]^T summed over 4 hi/lo terms.
// term t: A cols (t&1)*768.., B cols (t>>1)*768.. -> Ahi.Bhi+Alo.Bhi+Ahi.Blo+Alo.Blo.
template<bool RESID>
__global__ __launch_bounds__(256) void gemm_mfma4_k(const __hip_bfloat16* __restrict__ A,
                                                    const __hip_bfloat16* __restrict__ Bt,
                                                    float* __restrict__ C,
                                                    const float* __restrict__ R) {
    __shared__ unsigned short As[128][40];
    __shared__ unsigned short Bs[128][40];
    const int row0 = blockIdx.y * 128, col0 = blockIdx.x * 128;
    const int tid = threadIdx.x;
    const int lane = tid & 63, wid = tid >> 6;
    const int wr = (wid >> 1) * 64, wc = (wid & 1) * 64;
    const int lr = lane & 15, lkg = lane >> 4;
    const int srow = tid >> 1, skh = (tid & 1) * 16;
    const unsigned short* Ag = (const unsigned short*)A  + (size_t)(row0 + srow) * 1536 + skh;
    const unsigned short* Bg = (const unsigned short*)Bt + (size_t)(col0 + srow) * 1536 + skh;
    constexpr int NK = DD / 32;      // 24 k-steps per term
    constexpr int TOT = 4 * NK;      // 96 total
    f32x4 acc[4][4] = {};
    uint4 a0 = *(const uint4*)(Ag), a1 = *(const uint4*)(Ag + 8);
    uint4 b0 = *(const uint4*)(Bg), b1 = *(const uint4*)(Bg + 8);
    for (int it = 0; it < TOT; ++it) {
        __syncthreads();
        *(uint4*)&As[srow][skh]     = a0;
        *(uint4*)&As[srow][skh + 8] = a1;
        *(uint4*)&Bs[srow][skh]     = b0;
        *(uint4*)&Bs[srow][skh + 8] = b1;
        __syncthreads();
        int nit = it + 1;
        if (nit < TOT) {
            int nt = nit / NK, nk = (nit - nt * NK) * 32;
            int ca = (nt & 1) * DD + nk;
            int cb = (nt >> 1) * DD + nk;
            a0 = *(const uint4*)(Ag + ca); a1 = *(const uint4*)(Ag + ca + 8);
            b0 = *(const uint4*)(Bg + cb); b1 = *(const uint4*)(Bg + cb + 8);
        }
        bf16x8 af[4], bfr[4];
#pragma unroll
        for (int m = 0; m < 4; ++m)
            af[m] = *(const bf16x8*)&As[wr + m*16 + lr][lkg*8];
#pragma unroll
        for (int n = 0; n < 4; ++n)
            bfr[n] = *(const bf16x8*)&Bs[wc + n*16 + lr][lkg*8];
#pragma unroll
        for (int m = 0; m < 4; ++m)
#pragma unroll
            for (int n = 0; n < 4; ++n)
                acc[m][n] = __builtin_amdgcn_mfma_f32_16x16x32_bf16(af[m], bfr[n], acc[m][n], 0, 0, 0);
    }
#pragma unroll
    for (int m = 0; m < 4; ++m)
#pragma unroll
        for (int n = 0; n < 4; ++n)
#pragma unroll
            for (int r = 0; r < 4; ++r) {
                int rr = row0 + wr + m*16 + lkg*4 + r;
                int cc = col0 + wc + n*16 + lr;
                float v = acc[m][n][r];
                if (RESID) v += R[(size_t)rr * DD + cc];
                C[(size_t)rr * DD + cc] = v;
            }
}

// ---- Transpose + fp32->bf16 convert (FFN weights): in [K][N] -> out [N][K], batch z ----
__global__ __launch_bounds__(256) void transpose_cvt_k(const float* __restrict__ in,
                                                       __hip_bfloat16* __restrict__ outT,
                                                       int K, int N) {
    __shared__ float tile[32][33];
    const int z = blockIdx.z;
    in   += (size_t)z * K * N;
    outT += (size_t)z * K * N;
    const int n0 = blockIdx.x * 32, k0 = blockIdx.y * 32;
    const int tx = threadIdx.x & 31, ty = threadIdx.x >> 5;  // 32x8
#pragma unroll
    for (int i = 0; i < 4; ++i)
        tile[ty + 8*i][tx] = in[(size_t)(k0 + ty + 8*i) * N + n0 + tx];
    __syncthreads();
#pragma unroll
    for (int i = 0; i < 4; ++i)
        outT[(size_t)(n0 + ty + 8*i) * K + k0 + tx] = f2b(tile[tx][ty + 8*i]);
}

// ---- MFMA bf16 GEMM (FFN path): C[M,N](bf16) = A[M,K](bf16) @ Bt[N,K](bf16)^T.
template<bool RELU>
__global__ __launch_bounds__(256) void gemm_mfma_k(const __hip_bfloat16* __restrict__ A,
                                                   const __hip_bfloat16* __restrict__ Bt,
                                                   __hip_bfloat16* __restrict__ C,
                                                   int M, int N, int K,
                                                   long sA, long sB, long sC) {
    __shared__ unsigned short As[128][40];
    __shared__ unsigned short Bs[128][40];
    const int z = blockIdx.z;
    A  += (size_t)z * sA;
    Bt += (size_t)z * sB;
    C  += (size_t)z * sC;
    const int row0 = blockIdx.y * 128, col0 = blockIdx.x * 128;
    const int tid = threadIdx.x;
    const int lane = tid & 63, wid = tid >> 6;
    const int wr = (wid >> 1) * 64, wc = (wid & 1) * 64;
    const int lr = lane & 15, lkg = lane >> 4;
    const int srow = tid >> 1, skh = (tid & 1) * 16;

    const __hip_bfloat16* Ag = A  + (size_t)(row0 + srow) * K + skh;
    const __hip_bfloat16* Bg = Bt + (size_t)(col0 + srow) * K + skh;

    f32x4 acc[4][4] = {};
    uint4 a0 = *(const uint4*)(Ag);
    uint4 a1 = *(const uint4*)(Ag + 8);
    uint4 b0 = *(const uint4*)(Bg);
    uint4 b1 = *(const uint4*)(Bg + 8);
    for (int k0 = 0; k0 < K; k0 += 32) {
        __syncthreads();
        *(uint4*)&As[srow][skh]     = a0;
        *(uint4*)&As[srow][skh + 8] = a1;
        *(uint4*)&Bs[srow][skh]     = b0;
        *(uint4*)&Bs[srow][skh + 8] = b1;
        __syncthreads();
        if (k0 + 32 < K) {
            a0 = *(const uint4*)(Ag + k0 + 32);
            a1 = *(const uint4*)(Ag + k0 + 40);
            b0 = *(const uint4*)(Bg + k0 + 32);
            b1 = *(const uint4*)(Bg + k0 + 40);
        }
        bf16x8 af[4], bfr[4];
#pragma unroll
        for (int m = 0; m < 4; ++m)
            af[m] = *(const bf16x8*)&As[wr + m*16 + lr][lkg*8];
#pragma unroll
        for (int n = 0; n < 4; ++n)
            bfr[n] = *(const bf16x8*)&Bs[wc + n*16 + lr][lkg*8];
#pragma unroll
        for (int m = 0; m < 4; ++m)
#pragma unroll
            for (int n = 0; n < 4; ++n)
                acc[m][n] = __builtin_amdgcn_mfma_f32_16x16x32_bf16(af[m], bfr[n], acc[m][n], 0, 0, 0);
    }
#pragma unroll
    for (int m = 0; m < 4; ++m) {
#pragma unroll
        for (int n = 0; n < 4; ++n) {
#pragma unroll
            for (int r = 0; r < 4; ++r) {
                int rr = row0 + wr + m*16 + lkg*4 + r;
                int cc = col0 + wc + n*16 + lr;
                float v = acc[m][n][r];
                if (RELU) v = fmaxf(v, 0.f);
                C[(size_t)rr * N + cc] = f2b(v);
            }
        }
    }
}

// ==================== split-bf16 MFMA attention ====================

// Pack Q,K rows: per head write [Qhi(64)|Qlo(64)] into head-major [bh][n][128].
__global__ __launch_bounds__(256) void pack_qk_k(const float* __restrict__ qf,
                                                 const float* __restrict__ kf,
                                                 __hip_bfloat16* __restrict__ Aq,
                                                 __hip_bfloat16* __restrict__ Bk) {
    const int t = blockIdx.x * 16 + (threadIdx.x >> 4);
    const int quad = threadIdx.x & 15;
    const int b = t >> 10, n = t & 1023;
    const float* qp = qf + (size_t)t * DD;
    const float* kp = kf + (size_t)t * DD;
#pragma unroll
    for (int h = 0; h < HH; ++h) {
        float4 qv = *(const float4*)(qp + h*64 + quad*4);
        float4 kv = *(const float4*)(kp + h*64 + quad*4);
        size_t rowbase = ((size_t)(b*HH + h) * NN + n) * 128;
        float qa[4] = {qv.x,qv.y,qv.z,qv.w};
        float ka[4] = {kv.x,kv.y,kv.z,kv.w};
        unsigned short qh[4], ql[4], kh[4], kl[4];
#pragma unroll
        for (int j = 0; j < 4; ++j) {
            unsigned short hb = f2bu(qa[j]); qh[j]=hb; ql[j]=f2bu(qa[j]-bu2f(hb));
            unsigned short hc = f2bu(ka[j]); kh[j]=hc; kl[j]=f2bu(ka[j]-bu2f(hc));
        }
        unsigned short* aq = (unsigned short*)Aq + rowbase + quad*4;
        unsigned short* bk = (unsigned short*)Bk + rowbase + quad*4;
        *(uint2*)aq        = *(uint2*)qh;
        *(uint2*)(aq + 64) = *(uint2*)ql;
        *(uint2*)bk        = *(uint2*)kh;
        *(uint2*)(bk + 64) = *(uint2*)kl;
    }
}

// Pack V transposed: Vt[bh][d][0..1023]=Vhi^T, [d][1024..2047]=Vlo^T.
__global__ __launch_bounds__(256) void pack_v_k(const float* __restrict__ vf,
                                                __hip_bfloat16* __restrict__ Vt) {
    __shared__ float tile[32][65];
    const int bh = blockIdx.y, nt = blockIdx.x;
    const int b = bh / HH, h = bh % HH;
    const int n0 = nt * 32;
    const int tid = threadIdx.x;
    {
        int nr = tid >> 3, ds = (tid & 7) * 8;
        const float* vp = vf + ((size_t)(b*NN + n0 + nr) * DD) + h*64 + ds;
        float4 v0 = *(const float4*)vp;
        float4 v1 = *(const float4*)(vp + 4);
        tile[nr][ds+0]=v0.x; tile[nr][ds+1]=v0.y; tile[nr][ds+2]=v0.z; tile[nr][ds+3]=v0.w;
        tile[nr][ds+4]=v1.x; tile[nr][ds+5]=v1.y; tile[nr][ds+6]=v1.z; tile[nr][ds+7]=v1.w;
    }
    __syncthreads();
    {
        int d = tid >> 2, ns = (tid & 3) * 8;
        unsigned short hs[8], ls[8];
#pragma unroll
        for (int j = 0; j < 8; ++j) {
            float x = tile[ns+j][d];
            unsigned short hb = f2bu(x);
            hs[j] = hb; ls[j] = f2bu(x - bu2f(hb));
        }
        unsigned short* dst = (unsigned short*)Vt + ((size_t)bh*64 + d)*2048 + n0 + ns;
        *(uint4*)dst          = *(uint4*)hs;
        *(uint4*)(dst + 1024) = *(uint4*)ls;
    }
}

// Scores: S[z][1024][1024] fp32 = (Qhi+Qlo).(Khi+Klo) via Keff=256 wrapped MFMA.
__global__ __launch_bounds__(256) void attn_qk_k(const __hip_bfloat16* __restrict__ Aq,
                                                 const __hip_bfloat16* __restrict__ Bk,
                                                 float* __restrict__ S, int bh0) {
    __shared__ unsigned short As[128][40];
    __shared__ unsigned short Bs[128][40];
    const int z = blockIdx.z, bh = bh0 + z;
    const __hip_bfloat16* A  = Aq + (size_t)bh * NN * 128;
    const __hip_bfloat16* Bt = Bk + (size_t)bh * NN * 128;
    float* C = S + (size_t)z * NN * NN;
    const int row0 = blockIdx.y * 128, col0 = blockIdx.x * 128;
    const int tid = threadIdx.x;
    const int lane = tid & 63, wid = tid >> 6;
    const int wr = (wid >> 1) * 64, wc = (wid & 1) * 64;
    const int lr = lane & 15, lkg = lane >> 4;
    const int srow = tid >> 1, skh = (tid & 1) * 16;

    const __hip_bfloat16* Ag = A  + (size_t)(row0 + srow) * 128;
    const __hip_bfloat16* Bg = Bt + (size_t)(col0 + srow) * 128;

    f32x4 acc[4][4] = {};
    uint4 a0, a1, b0, b1;
    {
        int ka = skh & 127;
        a0 = *(const uint4*)(Ag + ka); a1 = *(const uint4*)(Ag + ka + 8);
        int kb = ((skh >> 7) << 6) | (skh & 63);
        b0 = *(const uint4*)(Bg + kb); b1 = *(const uint4*)(Bg + kb + 8);
    }
    for (int k0 = 0; k0 < 256; k0 += 32) {
        __syncthreads();
        *(uint4*)&As[srow][skh]     = a0;
        *(uint4*)&As[srow][skh + 8] = a1;
        *(uint4*)&Bs[srow][skh]     = b0;
        *(uint4*)&Bs[srow][skh + 8] = b1;
        __syncthreads();
        if (k0 + 32 < 256) {
            int kk = k0 + 32 + skh;
            int ka = kk & 127;
            a0 = *(const uint4*)(Ag + ka); a1 = *(const uint4*)(Ag + ka + 8);
            int kb = ((kk >> 7) << 6) | (kk & 63);
            b0 = *(const uint4*)(Bg + kb); b1 = *(const uint4*)(Bg + kb + 8);
        }
        bf16x8 af[4], bfr[4];
#pragma unroll
        for (int m = 0; m < 4; ++m)
            af[m] = *(const bf16x8*)&As[wr + m*16 + lr][lkg*8];
#pragma unroll
        for (int n = 0; n < 4; ++n)
            bfr[n] = *(const bf16x8*)&Bs[wc + n*16 + lr][lkg*8];
#pragma unroll
        for (int m = 0; m < 4; ++m)
#pragma unroll
            for (int n = 0; n < 4; ++n)
                acc[m][n] = __builtin_amdgcn_mfma_f32_16x16x32_bf16(af[m], bfr[n], acc[m][n], 0, 0, 0);
    }
#pragma unroll
    for (int m = 0; m < 4; ++m)
#pragma unroll
        for (int n = 0; n < 4; ++n)
#pragma unroll
            for (int r = 0; r < 4; ++r) {
                int rr = row0 + wr + m*16 + lkg*4 + r;
                int cc = col0 + wc + n*16 + lr;
                C[(size_t)rr * NN + cc] = acc[m][n][r];
            }
}

// Fused softmax + PV; epilogue writes ctx as hi/lo split pack [t][1536] for the
// O-projection's split-bf16 MFMA.
__global__ __launch_bounds__(256) void attn_pv_k(const float* __restrict__ S,
                                                 const __hip_bfloat16* __restrict__ Vt,
                                                 __hip_bfloat16* __restrict__ ctxs, int bh0) {
    __shared__ unsigned short Ahi[64][40], Alo[64][40];
    __shared__ unsigned short Bhi[64][40], Blo[64][40];
    __shared__ float mrow[64], irow[64];
    const int z = blockIdx.y, bh = bh0 + z;
    const int b = bh / HH, h = bh % HH;
    const int row0 = blockIdx.x * 64;
    const float* Sb = S + (size_t)z * NN * NN;
    const unsigned short* Vb = (const unsigned short*)Vt + (size_t)bh * 64 * 2048;
    const int tid = threadIdx.x, lane = tid & 63, wid = tid >> 6;
    const int lr = lane & 15, lkg = lane >> 4;

    {   // ---- stats: online max / sum-exp, 4 threads per row ----
        int r = tid >> 2, seg = tid & 3;
        const float4* sp = (const float4*)(Sb + (size_t)(row0 + r) * NN + seg * 256);
        float m = -1e30f, sum = 0.f;
#pragma unroll 8
        for (int j = 0; j < 64; ++j) {
            float4 v = sp[j];
            float m4 = fmaxf(fmaxf(v.x, v.y), fmaxf(v.z, v.w));
            float mn = fmaxf(m, m4);
            sum = sum * __expf(m - mn)
                + __expf(v.x - mn) + __expf(v.y - mn)
                + __expf(v.z - mn) + __expf(v.w - mn);
            m = mn;
        }
        float mo = __shfl_xor(m, 1), so = __shfl_xor(sum, 1);
        float M = fmaxf(m, mo); sum = sum*__expf(m - M) + so*__expf(mo - M); m = M;
        mo = __shfl_xor(m, 2); so = __shfl_xor(sum, 2);
        M = fmaxf(m, mo); sum = sum*__expf(m - M) + so*__expf(mo - M); m = M;
        if (seg == 0) { mrow[r] = m; irow[r] = 1.0f / sum; }
    }
    __syncthreads();

    const int ar = tid >> 2, aks = (tid & 3) * 8;
    const float* Ap = Sb + (size_t)(row0 + ar) * NN + aks;
    const float mr = mrow[ar], ir = irow[ar];
    const int vd = tid >> 2, vg = tid & 3;
    const int vhalf = vg >> 1, vks = (vg & 1) * 16;
    const unsigned short* Vp = Vb + (size_t)vd * 2048 + vhalf * 1024 + vks;

    f32x4 acc[4] = {};
    float4 sa0 = *(const float4*)(Ap);
    float4 sa1 = *(const float4*)(Ap + 4);
    uint4 vb0 = *(const uint4*)(Vp);
    uint4 vb1 = *(const uint4*)(Vp + 8);
    for (int kc = 0; kc < NN; kc += 32) {
        __syncthreads();
        {   // A tiles: exp + hi/lo split
            float sv[8] = {sa0.x,sa0.y,sa0.z,sa0.w, sa1.x,sa1.y,sa1.z,sa1.w};
            unsigned short hs[8], ls[8];
#pragma unroll
            for (int j = 0; j < 8; ++j) {
                float p = __expf(sv[j] - mr) * ir;
                unsigned short hb = f2bu(p);
                hs[j] = hb; ls[j] = f2bu(p - bu2f(hb));
            }
            *(uint4*)&Ahi[ar][aks] = *(uint4*)hs;
            *(uint4*)&Alo[ar][aks] = *(uint4*)ls;
        }
        {   // B tiles: direct copy
            unsigned short* dh = vhalf ? &Blo[vd][vks] : &Bhi[vd][vks];
            *(uint4*)dh       = vb0;
            *(uint4*)(dh + 8) = vb1;
        }
        __syncthreads();
        if (kc + 32 < NN) {
            sa0 = *(const float4*)(Ap + kc + 32);
            sa1 = *(const float4*)(Ap + kc + 36);
            vb0 = *(const uint4*)(Vp + kc + 32);
            vb1 = *(const uint4*)(Vp + kc + 40);
        }
        bf16x8 ah = *(const bf16x8*)&Ahi[wid*16 + lr][lkg*8];
        bf16x8 al = *(const bf16x8*)&Alo[wid*16 + lr][lkg*8];
#pragma unroll
        for (int n = 0; n < 4; ++n) {
            bf16x8 bhv = *(const bf16x8*)&Bhi[n*16 + lr][lkg*8];
            bf16x8 blv = *(const bf16x8*)&Blo[n*16 + lr][lkg*8];
            acc[n] = __builtin_amdgcn_mfma_f32_16x16x32_bf16(ah, bhv, acc[n], 0, 0, 0);
            acc[n] = __builtin_amdgcn_mfma_f32_16x16x32_bf16(al, bhv, acc[n], 0, 0, 0);
            acc[n] = __builtin_amdgcn_mfma_f32_16x16x32_bf16(ah, blv, acc[n], 0, 0, 0);
            acc[n] = __builtin_amdgcn_mfma_f32_16x16x32_bf16(al, blv, acc[n], 0, 0, 0);
        }
    }
#pragma unroll
    for (int n = 0; n < 4; ++n)
#pragma unroll
        for (int r2 = 0; r2 < 4; ++r2) {
            int row = row0 + wid*16 + lkg*4 + r2;
            int col = n*16 + lr;
            float v = acc[n][r2];
            unsigned short hb = f2bu(v);
            unsigned short lb = f2bu(v - bu2f(hb));
            unsigned short* cp = (unsigned short*)ctxs + (size_t)(b*NN + row) * 1536 + h*64 + col;
            cp[0]   = hb;
            cp[768] = lb;
        }
}

// ---- Gate: logits -> softmax -> top2 (+normalized gates), proxy/density accum
__global__ __launch_bounds__(256) void gate_k(const float* __restrict__ x,
                                              const float* __restrict__ gw,
                                              int* __restrict__ idx1, int* __restrict__ idx2,
                                              float* __restrict__ g1n, float* __restrict__ g2n,
                                              float* __restrict__ proxy, float* __restrict__ cnt1) {
    __shared__ float gws[DD*EE];
    for (int i = threadIdx.x; i < DD*EE; i += 256) gws[i] = gw[i];
    __syncthreads();
    int t = blockIdx.x * 256 + threadIdx.x;
    int b = t >> 10;
    float acc[EE] = {};
    const float4* xp = (const float4*)(x + (size_t)t * DD);
    for (int d4 = 0; d4 < DD/4; ++d4) {
        float4 xv = xp[d4];
        float xs[4] = {xv.x, xv.y, xv.z, xv.w};
#pragma unroll
        for (int qq = 0; qq < 4; ++qq) {
            const float* g = &gws[(d4*4+qq)*EE];
#pragma unroll
            for (int e = 0; e < EE; ++e) acc[e] += xs[qq] * g[e];
        }
    }
    float m = acc[0];
#pragma unroll
    for (int e = 1; e < EE; ++e) m = fmaxf(m, acc[e]);
    float sum = 0.f;
    float raw[EE];
#pragma unroll
    for (int e = 0; e < EE; ++e) { raw[e] = expf(acc[e] - m); sum += raw[e]; }
    float inv = 1.0f / sum;
#pragma unroll
    for (int e = 0; e < EE; ++e) raw[e] *= inv;
    int i1 = 0; float p1 = raw[0];
#pragma unroll
    for (int e = 1; e < EE; ++e) if (raw[e] > p1) { p1 = raw[e]; i1 = e; }
    int i2 = (i1 == 0) ? 1 : 0; float p2 = raw[i2];
#pragma unroll
    for (int e = 0; e < EE; ++e) if (e != i1 && raw[e] > p2) { p2 = raw[e]; i2 = e; }
    float den = p1 + p2 + 1e-9f;
    idx1[t] = i1; idx2[t] = i2;
    g1n[t] = p1 / den; g2n[t] = p2 / den;
    int ln = threadIdx.x & 63;
#pragma unroll
    for (int e = 0; e < EE; ++e) {
        float r = raw[e];
#pragma unroll
        for (int off = 1; off < 64; off <<= 1) r += __shfl_xor(r, off);
        if (ln == 0) atomicAdd(&proxy[b*EE + e], r);
    }
#pragma unroll
    for (int e = 0; e < EE; ++e) {
        unsigned long long mb = __ballot(i1 == e);
        if (ln == 0 && mb) atomicAdd(&cnt1[b*EE + e], (float)__popcll(mb));
    }
}

// ---- Capacity: parallel prefix-scan per (b,e). 128 blocks x 256 threads.
// Deterministic n-order => identical result to the sequential reference scan.
__global__ __launch_bounds__(256) void capacity_k(const int* __restrict__ idx1, const int* __restrict__ idx2,
                           const float* __restrict__ g1n, const float* __restrict__ g2n,
                           float* __restrict__ g1k, float* __restrict__ g2k,
                           int* __restrict__ pos1, int* __restrict__ pos2,
                           int* __restrict__ tokslot) {
    const int b = blockIdx.x >> 4, e = blockIdx.x & 15;
    const int tid = threadIdx.x, lane = tid & 63, wv = tid >> 6;
    const int base = b * NN;
    const int n0 = tid * 4;
    __shared__ int wsum[4];
    __shared__ int totsh;

    // ---- pass 1: idx1 ----
    int4 iv = *(const int4*)(idx1 + base + n0);
    int id[4] = {iv.x, iv.y, iv.z, iv.w};
    int cnt = 0;
#pragma unroll
    for (int j = 0; j < 4; ++j) cnt += (id[j] == e);
    int v = cnt;
#pragma unroll
    for (int off = 1; off < 64; off <<= 1) {
        int o = __shfl_up(v, off);
        if (lane >= off) v += o;
    }
    if (lane == 63) wsum[wv] = v;
    __syncthreads();
    int woff = 0;
#pragma unroll
    for (int w = 0; w < 4; ++w) if (w < wv) woff += wsum[w];
    int c = woff + v - cnt;   // exclusive prefix = sequential-scan position
    if (tid == 255) totsh = woff + v;
#pragma unroll
    for (int j = 0; j < 4; ++j) {
        if (id[j] == e) {
            int t = base + n0 + j;
            if (c < CAPX) {
                g1k[t] = g1n[t]; pos1[t] = c;
                tokslot[(e*BB + b)*CAPX + c] = t;
            } else { g1k[t] = 0.f; pos1[t] = 0; }
            c++;
        }
    }
    __syncthreads();
    const int m1c = totsh < CAPX ? totsh : CAPX;

    // ---- pass 2: idx2, slots offset by m1c ----
    iv = *(const int4*)(idx2 + base + n0);
    int id2[4] = {iv.x, iv.y, iv.z, iv.w};
    cnt = 0;
#pragma unroll
    for (int j = 0; j < 4; ++j) cnt += (id2[j] == e);
    v = cnt;
#pragma unroll
    for (int off = 1; off < 64; off <<= 1) {
        int o = __shfl_up(v, off);
        if (lane >= off) v += o;
    }
    if (lane == 63) wsum[wv] = v;
    __syncthreads();
    woff = 0;
#pragma unroll
    for (int w = 0; w < 4; ++w) if (w < wv) woff += wsum[w];
    c = woff + v - cnt + m1c;
#pragma unroll
    for (int j = 0; j < 4; ++j) {
        if (id2[j] == e) {
            int t = base + n0 + j;
            if (c < CAPX) {
                g2k[t] = g2n[t]; pos2[t] = c;
                tokslot[(e*BB + b)*CAPX + c] = t;
            } else { g2k[t] = 0.f; pos2[t] = 0; }
            c++;
        }
    }
}

// ---- Gather tokens into expert slots (zero-fill empty slots) ----
__global__ __launch_bounds__(256) void gather_k(const float* __restrict__ x,
                                                const int* __restrict__ tokslot,
                                                __hip_bfloat16* __restrict__ xin) {
    int sid = blockIdx.x;
    int t = tokslot[sid];
    __hip_bfloat16* op = xin + (size_t)sid * DD;
    if (t >= 0) {
        const float* xp = x + (size_t)t * DD;
        for (int d = threadIdx.x; d < DD; d += 256) op[d] = f2b(xp[d]);
    } else {
        for (int d = threadIdx.x; d < DD; d += 256) op[d] = f2b(0.f);
    }
}

// ---- Final combine: out(fp32) = h + g1*xo[e1,slot1] + g2*xo[e2,slot2] ----
__global__ __launch_bounds__(256) void combine_k(const float* __restrict__ h,
                                                 const __hip_bfloat16* __restrict__ xo,
                                                 const int* __restrict__ idx1, const int* __restrict__ idx2,
                                                 const int* __restrict__ pos1, const int* __restrict__ pos2,
                                                 const float* __restrict__ g1k, const float* __restrict__ g2k,
                                                 float* __restrict__ out) {
    int t = blockIdx.x;
    int b = t >> 10;
    float ga = g1k[t], gb = g2k[t];
    const __hip_bfloat16* xa = nullptr;
    const __hip_bfloat16* xb = nullptr;
    if (ga > 0.f) xa = xo + (size_t)((idx1[t]*BB + b)*CAPX + pos1[t]) * DD;
    if (gb > 0.f) xb = xo + (size_t)((idx2[t]*BB + b)*CAPX + pos2[t]) * DD;
    const float* hp = h + (size_t)t * DD;
    float* op = out + (size_t)t * DD;
    for (int d = threadIdx.x; d < DD; d += 256) {
        float v = hp[d];
        if (xa) v += ga * b2f(xa[d]);
        if (xb) v += gb * b2f(xb[d]);
        op[d] = v;
    }
}

// ---- Aux loss: mean(proxy*density)*E*E*coef -> fp32 scalar ----
__global__ void loss_k(const float* __restrict__ proxy, const float* __restrict__ cnt1,
                       float* __restrict__ out_loss) {
    int tid = threadIdx.x; // 128 threads, one per (b,e)
    float v = proxy[tid] * cnt1[tid];
#pragma unroll
    for (int off = 1; off < 64; off <<= 1) v += __shfl_xor(v, off);
    __shared__ float sm[2];
    if ((tid & 63) == 0) sm[tid >> 6] = v;
    __syncthreads();
    if (tid == 0) {
        float tot = sm[0] + sm[1];
        float loss = tot * (0.02f / (1024.f * 1024.f));
        *out_loss = loss;
    }
}

extern "C" void kernel_launch(void* const* d_in, const int* in_sizes, int n_in,
                              void* d_out, int out_size, void* d_ws, size_t ws_size,
                              hipStream_t stream) {
    const float* hid = (const float*)d_in[0];
    const float* ln0 = (const float*)d_in[2];
    const float* Wq  = (const float*)d_in[3];
    const float* Wk  = (const float*)d_in[4];
    const float* Wv  = (const float*)d_in[5];
    const float* Wo  = (const float*)d_in[6];
    const float* ln1 = (const float*)d_in[7];
    const float* gw  = (const float*)d_in[8];
    const float* w1  = (const float*)d_in[9];
    const float* w2  = (const float*)d_in[10];
    float* out = (float*)d_out;

    // ---- Workspace: 7 x SZ regions + weight-pack buffer (~178.7 MB total) ----
    // SZ = 25,165,824 B.  Liveness plan:
    //  R1: nsplit -> Vt2 -> wT(lo)
    //  R2: qf -> S_c(lo) -> wT(hi)
    //  R3: kf -> S_c(hi) -> hffn(lo)
    //  R4: vf -> csplit  -> hffn(hi)
    //  R5: Aq2 -> hres (live to end)
    //  R6: Bk2 -> normed2 -> xo
    //  R7: xin
    const size_t SZ = (size_t)NT * DD * 4;
    char* p = (char*)d_ws;
    auto alloc = [&](size_t bytes) { char* r = p; p += (bytes + 255) & ~(size_t)255; return (void*)r; };
    char* R1 = (char*)alloc(SZ);
    char* R2 = (char*)alloc(SZ);
    char* R3 = (char*)alloc(SZ);
    char* R4 = (char*)alloc(SZ);
    char* R5 = (char*)alloc(SZ);
    char* R6 = (char*)alloc(SZ);
    char* R7 = (char*)alloc(SZ);   // EE*BB*CAPX*DD*2 == SZ exactly
    __hip_bfloat16* wtbuf = (__hip_bfloat16*)alloc((size_t)DD * 1536 * 2);
    int*   idx1 = (int*)alloc(NT*4);
    int*   idx2 = (int*)alloc(NT*4);
    float* g1n  = (float*)alloc(NT*4);
    float* g2n  = (float*)alloc(NT*4);
    float* g1k  = (float*)alloc(NT*4);
    float* g2k  = (float*)alloc(NT*4);
    int*   pos1 = (int*)alloc(NT*4);
    int*   pos2 = (int*)alloc(NT*4);
    int*   tokslot = (int*)alloc(EE*BB*CAPX*4);
    float* proxy   = (float*)alloc(BB*EE*4);
    float* cnt1f   = (float*)alloc(BB*EE*4);
    size_t needed = (size_t)(p - (char*)d_ws);
    if (needed > ws_size) return;

    __hip_bfloat16* nsplit  = (__hip_bfloat16*)R1;
    float*          qf      = (float*)R2;
    float*          kf      = (float*)R3;
    float*          vf      = (float*)R4;
    __hip_bfloat16* Aq2     = (__hip_bfloat16*)R5;
    __hip_bfloat16* Bk2     = (__hip_bfloat16*)R6;
    __hip_bfloat16* Vt2     = (__hip_bfloat16*)R1;   // nsplit dead after QKV GEMMs
    float*          S_c     = (float*)R2;            // spans R2+R3 (qf/kf dead)
    __hip_bfloat16* csplit  = (__hip_bfloat16*)R4;   // vf dead after pack_v
    float*          hres    = (float*)R5;            // Aq2 dead after attention
    float*          normed2 = (float*)R6;            // Bk2 dead after attention
    __hip_bfloat16* wT      = (__hip_bfloat16*)R1;   // FFN: spans R1+R2
    __hip_bfloat16* hffn    = (__hip_bfloat16*)R3;   // FFN: spans R3+R4
    __hip_bfloat16* xo      = (__hip_bfloat16*)R6;   // normed2 dead after gather
    __hip_bfloat16* xin     = (__hip_bfloat16*)R7;

    (void)hipMemsetAsync(tokslot, 0xFF, EE*BB*CAPX*4, stream);
    (void)hipMemsetAsync(proxy, 0, BB*EE*4, stream);
    (void)hipMemsetAsync(cnt1f, 0, BB*EE*4, stream);

    // 1. RMSNorm(hidden) fused with hi/lo split pack
    rmsnorm_split_k<<<NT, 192, 0, stream>>>(hid, ln0, nsplit);
    // 2. Q,K,V projections via 4-term split-bf16 MFMA (~fp32 exact)
    dim3 gproj(DD/128, NT/128, 1);
    transpose_split_k<<<dim3(DD/32, DD/32), 256, 0, stream>>>(Wq, wtbuf);
    gemm_mfma4_k<false><<<gproj, 256, 0, stream>>>(nsplit, wtbuf, qf, nullptr);
    transpose_split_k<<<dim3(DD/32, DD/32), 256, 0, stream>>>(Wk, wtbuf);
    gemm_mfma4_k<false><<<gproj, 256, 0, stream>>>(nsplit, wtbuf, kf, nullptr);
    transpose_split_k<<<dim3(DD/32, DD/32), 256, 0, stream>>>(Wv, wtbuf);
    gemm_mfma4_k<false><<<gproj, 256, 0, stream>>>(nsplit, wtbuf, vf, nullptr);
    // 3. Attention via split-bf16 MFMA; pv epilogue writes ctx hi/lo pack
    pack_qk_k<<<NT/16, 256, 0, stream>>>(qf, kf, Aq2, Bk2);
    pack_v_k<<<dim3(NN/32, BB*HH), 256, 0, stream>>>(vf, Vt2);
    for (int c = 0; c < 8; ++c) {
        int bh0 = c * HH;  // chunk of 12 (b,h) pairs; S_c reused per chunk
        attn_qk_k<<<dim3(NN/128, NN/128, HH), 256, 0, stream>>>(Aq2, Bk2, S_c, bh0);
        attn_pv_k<<<dim3(NN/64, HH), 256, 0, stream>>>(S_c, Vt2, csplit, bh0);
    }
    // 4. O-projection (split-bf16 MFMA) + residual -> h (fp32)
    transpose_split_k<<<dim3(DD/32, DD/32), 256, 0, stream>>>(Wo, wtbuf);
    gemm_mfma4_k<true><<<gproj, 256, 0, stream>>>(csplit, wtbuf, hres, hid);
    // 5. RMSNorm(h) fp32
    rmsnorm_k<float><<<NT, 256, 0, stream>>>(hres, ln1, normed2);
    // 6. Gating
    gate_k<<<NT/256, 256, 0, stream>>>(normed2, gw, idx1, idx2, g1n, g2n, proxy, cnt1f);
    // 7. Capacity assignment (parallel prefix scan, order-identical to serial)
    capacity_k<<<BB*EE, 256, 0, stream>>>(idx1, idx2, g1n, g2n, g1k, g2k, pos1, pos2, tokslot);
    // 8. Gather into expert slots (fp32 -> bf16)
    gather_k<<<EE*BB*CAPX, 256, 0, stream>>>(normed2, tokslot, xin);
    // 9/10. Expert FFN via bf16 MFMA, 2 groups of 8 experts
    for (int g = 0; g < 2; ++g) {
        const int e0 = g * 8;
        transpose_cvt_k<<<dim3(DFF/32, DD/32, 8), 256, 0, stream>>>(
            w1 + (size_t)e0*DD*DFF, wT, DD, DFF);
        gemm_mfma_k<true><<<dim3(DFF/128, (BB*CAPX)/128, 8), 256, 0, stream>>>(
            xin + (size_t)e0*BB*CAPX*DD, wT, hffn,
            BB*CAPX, DFF, DD,
            (long)BB*CAPX*DD, (long)DD*DFF, (long)BB*CAPX*DFF);
        transpose_cvt_k<<<dim3(DD/32, DFF/32, 8), 256, 0, stream>>>(
            w2 + (size_t)e0*DFF*DD, wT, DFF, DD);
        gemm_mfma_k<false><<<dim3(DD/128, (BB*CAPX)/128, 8), 256, 0, stream>>>(
            hffn, wT, xo + (size_t)e0*BB*CAPX*DD,
            BB*CAPX, DD, DFF,
            (long)BB*CAPX*DFF, (long)DFF*DD, (long)BB*CAPX*DD);
    }
    // 11. Combine + residual -> output (fp32)
    combine_k<<<NT, 256, 0, stream>>>(hres, xo, idx1, idx2, pos1, pos2, g1k, g2k, out);
    // 12. Aux loss scalar (fp32)
    loss_k<<<1, 128, 0, stream>>>(proxy, cnt1f, out + (size_t)NT*DD);
}

// Round 4
// 1336.357 us; speedup vs baseline: 4.0393x; 1.1474x over previous
//
#include <hip/hip_runtime.h>
#include <hip/hip_bf16.h>

#define BB 8
#define NN 1024
#define DD 768
#define HH 12
#define DKVX 64
#define DFF 3072
#define EE 16
#define CAPX 128
#define NT (BB*NN)   // 8192 tokens

typedef __attribute__((ext_vector_type(8))) short bf16x8;
typedef __attribute__((ext_vector_type(4))) float f32x4;

__device__ __forceinline__ float b2f(__hip_bfloat16 x) { return __bfloat162float(x); }
__device__ __forceinline__ __hip_bfloat16 f2b(float x) { return __float2bfloat16(x); }
__device__ __forceinline__ float toFloat(float x) { return x; }
__device__ __forceinline__ float toFloat(__hip_bfloat16 x) { return __bfloat162float(x); }

// bf16 bit helpers for exact hi/lo splitting (x == hi + lo to ~2^-18 rel)
__device__ __forceinline__ unsigned short f2bu(float x) {
    __hip_bfloat16 h = __float2bfloat16(x);
    return *reinterpret_cast<unsigned short*>(&h);
}
__device__ __forceinline__ float bu2f(unsigned short u) {
    return __uint_as_float(((unsigned int)u) << 16);
}

// ---- RMSNorm (T5) fp32 out ----
template<typename TIN>
__global__ __launch_bounds__(256) void rmsnorm_k(const TIN* __restrict__ x,
                                                 const float* __restrict__ w,
                                                 float* __restrict__ out) {
    int t = blockIdx.x;
    int tid = threadIdx.x;
    const TIN* xp = x + (size_t)t * DD;
    float xv[3];
    float s = 0.f;
#pragma unroll
    for (int i = 0; i < 3; ++i) {
        float v = toFloat(xp[tid + i*256]);
        xv[i] = v; s += v*v;
    }
#pragma unroll
    for (int off = 1; off < 64; off <<= 1) s += __shfl_xor(s, off);
    __shared__ float sm[8];
    int wv = tid >> 6, ln = tid & 63;
    if (ln == 0) sm[wv] = s;
    __syncthreads();
    if (tid == 0) {
        float tot = sm[0]+sm[1]+sm[2]+sm[3];
        sm[4] = 1.0f / sqrtf(tot / (float)DD + 1e-6f);
    }
    __syncthreads();
    float sc = sm[4];
    float* op = out + (size_t)t * DD;
#pragma unroll
    for (int i = 0; i < 3; ++i) {
        int d = tid + i*256;
        op[d] = xv[i] * sc * w[d];
    }
}

// ---- RMSNorm fused with hi/lo split pack: out bf16 [t][1536] = [hi(768)|lo(768)] ----
__global__ __launch_bounds__(192) void rmsnorm_split_k(const float* __restrict__ x,
                                                       const float* __restrict__ w,
                                                       __hip_bfloat16* __restrict__ out) {
    int t = blockIdx.x, tid = threadIdx.x;
    float4 xv = *(const float4*)(x + (size_t)t * DD + tid * 4);
    float s = xv.x*xv.x + xv.y*xv.y + xv.z*xv.z + xv.w*xv.w;
#pragma unroll
    for (int off = 1; off < 64; off <<= 1) s += __shfl_xor(s, off);
    __shared__ float sm[4];
    int wv = tid >> 6, ln = tid & 63;
    if (ln == 0) sm[wv] = s;
    __syncthreads();
    if (tid == 0) sm[3] = 1.0f / sqrtf((sm[0]+sm[1]+sm[2]) / (float)DD + 1e-6f);
    __syncthreads();
    float sc = sm[3];
    float4 wv4 = *(const float4*)(w + tid * 4);
    float y[4] = {xv.x*sc*wv4.x, xv.y*sc*wv4.y, xv.z*sc*wv4.z, xv.w*sc*wv4.w};
    unsigned short hs[4], ls[4];
#pragma unroll
    for (int j = 0; j < 4; ++j) {
        hs[j] = f2bu(y[j]);
        ls[j] = f2bu(y[j] - bu2f(hs[j]));
    }
    unsigned short* op = (unsigned short*)out + (size_t)t * 1536 + tid * 4;
    *(uint2*)op         = *(uint2*)hs;
    *(uint2*)(op + 768) = *(uint2*)ls;
}

// ---- Weight transpose + hi/lo split: in [768][768] fp32 -> out [768][1536] bf16 ----
__global__ __launch_bounds__(256) void transpose_split_k(const float* __restrict__ in,
                                                         __hip_bfloat16* __restrict__ outT) {
    __shared__ float tile[32][33];
    const int n0 = blockIdx.x * 32, k0 = blockIdx.y * 32;
    const int tx = threadIdx.x & 31, ty = threadIdx.x >> 5;  // 32x8
#pragma unroll
    for (int i = 0; i < 4; ++i)
        tile[ty + 8*i][tx] = in[(size_t)(k0 + ty + 8*i) * DD + n0 + tx];
    __syncthreads();
#pragma unroll
    for (int i = 0; i < 4; ++i) {
        float x = tile[tx][ty + 8*i];
        unsigned short hb = f2bu(x);
        unsigned short lb = f2bu(x - bu2f(hb));
        unsigned short* op = (unsigned short*)outT + (size_t)(n0 + ty + 8*i) * 1536 + k0 + tx;
        op[0]   = hb;
        op[768] = lb;
    }
}

// ---- Fused QKV weight pack: z selects Wq/Wk/Wv -> out rows [z*768 .. z*768+767] ----
__global__ __launch_bounds__(256) void transpose_split3_k(const float* __restrict__ Wq,
                                                          const float* __restrict__ Wk,
                                                          const float* __restrict__ Wv,
                                                          __hip_bfloat16* __restrict__ outT) {
    __shared__ float tile[32][33];
    const int z = blockIdx.z;
    const float* in = (z == 0) ? Wq : (z == 1) ? Wk : Wv;
    unsigned short* ob = (unsigned short*)outT + (size_t)z * 768 * 1536;
    const int n0 = blockIdx.x * 32, k0 = blockIdx.y * 32;
    const int tx = threadIdx.x & 31, ty = threadIdx.x >> 5;
#pragma unroll
    for (int i = 0; i < 4; ++i)
        tile[ty + 8*i][tx] = in[(size_t)(k0 + ty + 8*i) * DD + n0 + tx];
    __syncthreads();
#pragma unroll
    for (int i = 0; i < 4; ++i) {
        float x = tile[tx][ty + 8*i];
        unsigned short hb = f2bu(x);
        unsigned short lb = f2bu(x - bu2f(hb));
        unsigned short* op = ob + (size_t)(n0 + ty + 8*i) * 1536 + k0 + tx;
        op[0]   = hb;
        op[768] = lb;
    }
}

// ---- Fused QKV projection: 4-term split-bf16 MFMA, N=2304, XCD-swizzled 1D grid.
// Epilogue: q/k sections packed hi/lo into attention layouts; v section -> fp32.
__global__ __launch_bounds__(256) void gemm_qkv_k(const __hip_bfloat16* __restrict__ A,
                                                  const __hip_bfloat16* __restrict__ Bt,
                                                  __hip_bfloat16* __restrict__ Aq,
                                                  __hip_bfloat16* __restrict__ Bk,
                                                  float* __restrict__ vf) {
    __shared__ unsigned short As[128][40];
    __shared__ unsigned short Bs[128][40];
    // swizzle: XCD (b%8) owns row-panels 8*xcd..8*xcd+7, sweeping cols fastest
    const int bb = blockIdx.x;
    const int xcd = bb & 7, ii = bb >> 3;          // ii in [0,144)
    const int row0 = (xcd * 8 + ii / 18) * 128;
    const int col  = ii % 18;
    const int col0 = col * 128;
    const int tid = threadIdx.x;
    const int lane = tid & 63, wid = tid >> 6;
    const int wr = (wid >> 1) * 64, wc = (wid & 1) * 64;
    const int lr = lane & 15, lkg = lane >> 4;
    const int srow = tid >> 1, skh = (tid & 1) * 16;
    const unsigned short* Ag = (const unsigned short*)A  + (size_t)(row0 + srow) * 1536 + skh;
    const unsigned short* Bg = (const unsigned short*)Bt + (size_t)(col0 + srow) * 1536 + skh;
    constexpr int NK = DD / 32;      // 24 k-steps per term
    constexpr int TOT = 4 * NK;      // 96 total
    f32x4 acc[4][4] = {};
    uint4 a0 = *(const uint4*)(Ag), a1 = *(const uint4*)(Ag + 8);
    uint4 b0 = *(const uint4*)(Bg), b1 = *(const uint4*)(Bg + 8);
    for (int it = 0; it < TOT; ++it) {
        __syncthreads();
        *(uint4*)&As[srow][skh]     = a0;
        *(uint4*)&As[srow][skh + 8] = a1;
        *(uint4*)&Bs[srow][skh]     = b0;
        *(uint4*)&Bs[srow][skh + 8] = b1;
        __syncthreads();
        int nit = it + 1;
        if (nit < TOT) {
            int nt = nit / NK, nk = (nit - nt * NK) * 32;
            int ca = (nt & 1) * DD + nk;
            int cb = (nt >> 1) * DD + nk;
            a0 = *(const uint4*)(Ag + ca); a1 = *(const uint4*)(Ag + ca + 8);
            b0 = *(const uint4*)(Bg + cb); b1 = *(const uint4*)(Bg + cb + 8);
        }
        bf16x8 af[4], bfr[4];
#pragma unroll
        for (int m = 0; m < 4; ++m)
            af[m] = *(const bf16x8*)&As[wr + m*16 + lr][lkg*8];
#pragma unroll
        for (int n = 0; n < 4; ++n)
            bfr[n] = *(const bf16x8*)&Bs[wc + n*16 + lr][lkg*8];
#pragma unroll
        for (int m = 0; m < 4; ++m)
#pragma unroll
            for (int n = 0; n < 4; ++n)
                acc[m][n] = __builtin_amdgcn_mfma_f32_16x16x32_bf16(af[m], bfr[n], acc[m][n], 0, 0, 0);
    }
    const int sec = col / 6;                 // 0=q 1=k 2=v (128 | 768)
    const int cbase = col0 - sec * 768;
    unsigned short* PK = (unsigned short*)(sec == 0 ? Aq : Bk);
#pragma unroll
    for (int m = 0; m < 4; ++m)
#pragma unroll
        for (int n = 0; n < 4; ++n)
#pragma unroll
            for (int r = 0; r < 4; ++r) {
                int rr = row0 + wr + m*16 + lkg*4 + r;
                int cin = cbase + wc + n*16 + lr;
                float v = acc[m][n][r];
                if (sec == 2) {
                    vf[(size_t)rr * DD + cin] = v;
                } else {
                    int h = cin >> 6, d = cin & 63;
                    int bq = rr >> 10, nn2 = rr & 1023;
                    unsigned short hb = f2bu(v);
                    unsigned short lb = f2bu(v - bu2f(hb));
                    unsigned short* dst = PK + ((size_t)(bq*HH + h) * NN + nn2) * 128 + d;
                    dst[0]  = hb;
                    dst[64] = lb;
                }
            }
}

// ---- O-projection: 4-term split-bf16 MFMA, fp32 C + residual, XCD-swizzled ----
__global__ __launch_bounds__(256) void gemm_mfma4_k(const __hip_bfloat16* __restrict__ A,
                                                    const __hip_bfloat16* __restrict__ Bt,
                                                    float* __restrict__ C,
                                                    const float* __restrict__ R) {
    __shared__ unsigned short As[128][40];
    __shared__ unsigned short Bs[128][40];
    const int bb = blockIdx.x;                    // 384 blocks
    const int xcd = bb & 7, ii = bb >> 3;         // ii in [0,48)
    const int row0 = (xcd * 8 + ii / 6) * 128;
    const int col0 = (ii % 6) * 128;
    const int tid = threadIdx.x;
    const int lane = tid & 63, wid = tid >> 6;
    const int wr = (wid >> 1) * 64, wc = (wid & 1) * 64;
    const int lr = lane & 15, lkg = lane >> 4;
    const int srow = tid >> 1, skh = (tid & 1) * 16;
    const unsigned short* Ag = (const unsigned short*)A  + (size_t)(row0 + srow) * 1536 + skh;
    const unsigned short* Bg = (const unsigned short*)Bt + (size_t)(col0 + srow) * 1536 + skh;
    constexpr int NK = DD / 32;
    constexpr int TOT = 4 * NK;
    f32x4 acc[4][4] = {};
    uint4 a0 = *(const uint4*)(Ag), a1 = *(const uint4*)(Ag + 8);
    uint4 b0 = *(const uint4*)(Bg), b1 = *(const uint4*)(Bg + 8);
    for (int it = 0; it < TOT; ++it) {
        __syncthreads();
        *(uint4*)&As[srow][skh]     = a0;
        *(uint4*)&As[srow][skh + 8] = a1;
        *(uint4*)&Bs[srow][skh]     = b0;
        *(uint4*)&Bs[srow][skh + 8] = b1;
        __syncthreads();
        int nit = it + 1;
        if (nit < TOT) {
            int nt = nit / NK, nk = (nit - nt * NK) * 32;
            int ca = (nt & 1) * DD + nk;
            int cb = (nt >> 1) * DD + nk;
            a0 = *(const uint4*)(Ag + ca); a1 = *(const uint4*)(Ag + ca + 8);
            b0 = *(const uint4*)(Bg + cb); b1 = *(const uint4*)(Bg + cb + 8);
        }
        bf16x8 af[4], bfr[4];
#pragma unroll
        for (int m = 0; m < 4; ++m)
            af[m] = *(const bf16x8*)&As[wr + m*16 + lr][lkg*8];
#pragma unroll
        for (int n = 0; n < 4; ++n)
            bfr[n] = *(const bf16x8*)&Bs[wc + n*16 + lr][lkg*8];
#pragma unroll
        for (int m = 0; m < 4; ++m)
#pragma unroll
            for (int n = 0; n < 4; ++n)
                acc[m][n] = __builtin_amdgcn_mfma_f32_16x16x32_bf16(af[m], bfr[n], acc[m][n], 0, 0, 0);
    }
#pragma unroll
    for (int m = 0; m < 4; ++m)
#pragma unroll
        for (int n = 0; n < 4; ++n)
#pragma unroll
            for (int r = 0; r < 4; ++r) {
                int rr = row0 + wr + m*16 + lkg*4 + r;
                int cc = col0 + wc + n*16 + lr;
                C[(size_t)rr * DD + cc] = acc[m][n][r] + R[(size_t)rr * DD + cc];
            }
}

// ---- Transpose + fp32->bf16 convert (FFN weights) ----
__global__ __launch_bounds__(256) void transpose_cvt_k(const float* __restrict__ in,
                                                       __hip_bfloat16* __restrict__ outT,
                                                       int K, int N) {
    __shared__ float tile[32][33];
    const int z = blockIdx.z;
    in   += (size_t)z * K * N;
    outT += (size_t)z * K * N;
    const int n0 = blockIdx.x * 32, k0 = blockIdx.y * 32;
    const int tx = threadIdx.x & 31, ty = threadIdx.x >> 5;
#pragma unroll
    for (int i = 0; i < 4; ++i)
        tile[ty + 8*i][tx] = in[(size_t)(k0 + ty + 8*i) * N + n0 + tx];
    __syncthreads();
#pragma unroll
    for (int i = 0; i < 4; ++i)
        outT[(size_t)(n0 + ty + 8*i) * K + k0 + tx] = f2b(tile[tx][ty + 8*i]);
}

// ---- MFMA bf16 GEMM (FFN): XCD-swizzled 1D grid, z = expert = XCD id ----
template<bool RELU>
__global__ __launch_bounds__(256) void gemm_mfma_k(const __hip_bfloat16* __restrict__ A,
                                                   const __hip_bfloat16* __restrict__ Bt,
                                                   __hip_bfloat16* __restrict__ C,
                                                   int N, int K, int nx,
                                                   long sA, long sB, long sC) {
    __shared__ unsigned short As[128][40];
    __shared__ unsigned short Bs[128][40];
    const int bb = blockIdx.x;
    const int z = bb & 7, ii = bb >> 3;
    const int row0 = (ii / nx) * 128, col0 = (ii % nx) * 128;
    A  += (size_t)z * sA;
    Bt += (size_t)z * sB;
    C  += (size_t)z * sC;
    const int tid = threadIdx.x;
    const int lane = tid & 63, wid = tid >> 6;
    const int wr = (wid >> 1) * 64, wc = (wid & 1) * 64;
    const int lr = lane & 15, lkg = lane >> 4;
    const int srow = tid >> 1, skh = (tid & 1) * 16;

    const __hip_bfloat16* Ag = A  + (size_t)(row0 + srow) * K + skh;
    const __hip_bfloat16* Bg = Bt + (size_t)(col0 + srow) * K + skh;

    f32x4 acc[4][4] = {};
    uint4 a0 = *(const uint4*)(Ag);
    uint4 a1 = *(const uint4*)(Ag + 8);
    uint4 b0 = *(const uint4*)(Bg);
    uint4 b1 = *(const uint4*)(Bg + 8);
    for (int k0 = 0; k0 < K; k0 += 32) {
        __syncthreads();
        *(uint4*)&As[srow][skh]     = a0;
        *(uint4*)&As[srow][skh + 8] = a1;
        *(uint4*)&Bs[srow][skh]     = b0;
        *(uint4*)&Bs[srow][skh + 8] = b1;
        __syncthreads();
        if (k0 + 32 < K) {
            a0 = *(const uint4*)(Ag + k0 + 32);
            a1 = *(const uint4*)(Ag + k0 + 40);
            b0 = *(const uint4*)(Bg + k0 + 32);
            b1 = *(const uint4*)(Bg + k0 + 40);
        }
        bf16x8 af[4], bfr[4];
#pragma unroll
        for (int m = 0; m < 4; ++m)
            af[m] = *(const bf16x8*)&As[wr + m*16 + lr][lkg*8];
#pragma unroll
        for (int n = 0; n < 4; ++n)
            bfr[n] = *(const bf16x8*)&Bs[wc + n*16 + lr][lkg*8];
#pragma unroll
        for (int m = 0; m < 4; ++m)
#pragma unroll
            for (int n = 0; n < 4; ++n)
                acc[m][n] = __builtin_amdgcn_mfma_f32_16x16x32_bf16(af[m], bfr[n], acc[m][n], 0, 0, 0);
    }
#pragma unroll
    for (int m = 0; m < 4; ++m) {
#pragma unroll
        for (int n = 0; n < 4; ++n) {
#pragma unroll
            for (int r = 0; r < 4; ++r) {
                int rr = row0 + wr + m*16 + lkg*4 + r;
                int cc = col0 + wc + n*16 + lr;
                float v = acc[m][n][r];
                if (RELU) v = fmaxf(v, 0.f);
                C[(size_t)rr * N + cc] = f2b(v);
            }
        }
    }
}

// ==================== split-bf16 MFMA attention ====================

// Pack V transposed: Vt[bh][d][0..1023]=Vhi^T, [d][1024..2047]=Vlo^T.
__global__ __launch_bounds__(256) void pack_v_k(const float* __restrict__ vf,
                                                __hip_bfloat16* __restrict__ Vt) {
    __shared__ float tile[32][65];
    const int bh = blockIdx.y, nt = blockIdx.x;
    const int b = bh / HH, h = bh % HH;
    const int n0 = nt * 32;
    const int tid = threadIdx.x;
    {
        int nr = tid >> 3, ds = (tid & 7) * 8;
        const float* vp = vf + ((size_t)(b*NN + n0 + nr) * DD) + h*64 + ds;
        float4 v0 = *(const float4*)vp;
        float4 v1 = *(const float4*)(vp + 4);
        tile[nr][ds+0]=v0.x; tile[nr][ds+1]=v0.y; tile[nr][ds+2]=v0.z; tile[nr][ds+3]=v0.w;
        tile[nr][ds+4]=v1.x; tile[nr][ds+5]=v1.y; tile[nr][ds+6]=v1.z; tile[nr][ds+7]=v1.w;
    }
    __syncthreads();
    {
        int d = tid >> 2, ns = (tid & 3) * 8;
        unsigned short hs[8], ls[8];
#pragma unroll
        for (int j = 0; j < 8; ++j) {
            float x = tile[ns+j][d];
            unsigned short hb = f2bu(x);
            hs[j] = hb; ls[j] = f2bu(x - bu2f(hb));
        }
        unsigned short* dst = (unsigned short*)Vt + ((size_t)bh*64 + d)*2048 + n0 + ns;
        *(uint4*)dst          = *(uint4*)hs;
        *(uint4*)(dst + 1024) = *(uint4*)ls;
    }
}

// Scores: S[z][1024][1024] fp32 = (Qhi+Qlo).(Khi+Klo) via Keff=256 wrapped MFMA.
__global__ __launch_bounds__(256) void attn_qk_k(const __hip_bfloat16* __restrict__ Aq,
                                                 const __hip_bfloat16* __restrict__ Bk,
                                                 float* __restrict__ S, int bh0) {
    __shared__ unsigned short As[128][40];
    __shared__ unsigned short Bs[128][40];
    const int z = blockIdx.z, bh = bh0 + z;
    const __hip_bfloat16* A  = Aq + (size_t)bh * NN * 128;
    const __hip_bfloat16* Bt = Bk + (size_t)bh * NN * 128;
    float* C = S + (size_t)z * NN * NN;
    const int row0 = blockIdx.y * 128, col0 = blockIdx.x * 128;
    const int tid = threadIdx.x;
    const int lane = tid & 63, wid = tid >> 6;
    const int wr = (wid >> 1) * 64, wc = (wid & 1) * 64;
    const int lr = lane & 15, lkg = lane >> 4;
    const int srow = tid >> 1, skh = (tid & 1) * 16;

    const __hip_bfloat16* Ag = A  + (size_t)(row0 + srow) * 128;
    const __hip_bfloat16* Bg = Bt + (size_t)(col0 + srow) * 128;

    f32x4 acc[4][4] = {};
    uint4 a0, a1, b0, b1;
    {
        int ka = skh & 127;
        a0 = *(const uint4*)(Ag + ka); a1 = *(const uint4*)(Ag + ka + 8);
        int kb = ((skh >> 7) << 6) | (skh & 63);
        b0 = *(const uint4*)(Bg + kb); b1 = *(const uint4*)(Bg + kb + 8);
    }
    for (int k0 = 0; k0 < 256; k0 += 32) {
        __syncthreads();
        *(uint4*)&As[srow][skh]     = a0;
        *(uint4*)&As[srow][skh + 8] = a1;
        *(uint4*)&Bs[srow][skh]     = b0;
        *(uint4*)&Bs[srow][skh + 8] = b1;
        __syncthreads();
        if (k0 + 32 < 256) {
            int kk = k0 + 32 + skh;
            int ka = kk & 127;
            a0 = *(const uint4*)(Ag + ka); a1 = *(const uint4*)(Ag + ka + 8);
            int kb = ((kk >> 7) << 6) | (kk & 63);
            b0 = *(const uint4*)(Bg + kb); b1 = *(const uint4*)(Bg + kb + 8);
        }
        bf16x8 af[4], bfr[4];
#pragma unroll
        for (int m = 0; m < 4; ++m)
            af[m] = *(const bf16x8*)&As[wr + m*16 + lr][lkg*8];
#pragma unroll
        for (int n = 0; n < 4; ++n)
            bfr[n] = *(const bf16x8*)&Bs[wc + n*16 + lr][lkg*8];
#pragma unroll
        for (int m = 0; m < 4; ++m)
#pragma unroll
            for (int n = 0; n < 4; ++n)
                acc[m][n] = __builtin_amdgcn_mfma_f32_16x16x32_bf16(af[m], bfr[n], acc[m][n], 0, 0, 0);
    }
#pragma unroll
    for (int m = 0; m < 4; ++m)
#pragma unroll
        for (int n = 0; n < 4; ++n)
#pragma unroll
            for (int r = 0; r < 4; ++r) {
                int rr = row0 + wr + m*16 + lkg*4 + r;
                int cc = col0 + wc + n*16 + lr;
                C[(size_t)rr * NN + cc] = acc[m][n][r];
            }
}

// Fused softmax + PV; epilogue writes ctx as hi/lo split pack [t][1536].
__global__ __launch_bounds__(256) void attn_pv_k(const float* __restrict__ S,
                                                 const __hip_bfloat16* __restrict__ Vt,
                                                 __hip_bfloat16* __restrict__ ctxs, int bh0) {
    __shared__ unsigned short Ahi[64][40], Alo[64][40];
    __shared__ unsigned short Bhi[64][40], Blo[64][40];
    __shared__ float mrow[64], irow[64];
    const int z = blockIdx.y, bh = bh0 + z;
    const int b = bh / HH, h = bh % HH;
    const int row0 = blockIdx.x * 64;
    const float* Sb = S + (size_t)z * NN * NN;
    const unsigned short* Vb = (const unsigned short*)Vt + (size_t)bh * 64 * 2048;
    const int tid = threadIdx.x, lane = tid & 63, wid = tid >> 6;
    const int lr = lane & 15, lkg = lane >> 4;

    {   // ---- stats: online max / sum-exp, 4 threads per row ----
        int r = tid >> 2, seg = tid & 3;
        const float4* sp = (const float4*)(Sb + (size_t)(row0 + r) * NN + seg * 256);
        float m = -1e30f, sum = 0.f;
#pragma unroll 8
        for (int j = 0; j < 64; ++j) {
            float4 v = sp[j];
            float m4 = fmaxf(fmaxf(v.x, v.y), fmaxf(v.z, v.w));
            float mn = fmaxf(m, m4);
            sum = sum * __expf(m - mn)
                + __expf(v.x - mn) + __expf(v.y - mn)
                + __expf(v.z - mn) + __expf(v.w - mn);
            m = mn;
        }
        float mo = __shfl_xor(m, 1), so = __shfl_xor(sum, 1);
        float M = fmaxf(m, mo); sum = sum*__expf(m - M) + so*__expf(mo - M); m = M;
        mo = __shfl_xor(m, 2); so = __shfl_xor(sum, 2);
        M = fmaxf(m, mo); sum = sum*__expf(m - M) + so*__expf(mo - M); m = M;
        if (seg == 0) { mrow[r] = m; irow[r] = 1.0f / sum; }
    }
    __syncthreads();

    const int ar = tid >> 2, aks = (tid & 3) * 8;
    const float* Ap = Sb + (size_t)(row0 + ar) * NN + aks;
    const float mr = mrow[ar], ir = irow[ar];
    const int vd = tid >> 2, vg = tid & 3;
    const int vhalf = vg >> 1, vks = (vg & 1) * 16;
    const unsigned short* Vp = Vb + (size_t)vd * 2048 + vhalf * 1024 + vks;

    f32x4 acc[4] = {};
    float4 sa0 = *(const float4*)(Ap);
    float4 sa1 = *(const float4*)(Ap + 4);
    uint4 vb0 = *(const uint4*)(Vp);
    uint4 vb1 = *(const uint4*)(Vp + 8);
    for (int kc = 0; kc < NN; kc += 32) {
        __syncthreads();
        {   // A tiles: exp + hi/lo split
            float sv[8] = {sa0.x,sa0.y,sa0.z,sa0.w, sa1.x,sa1.y,sa1.z,sa1.w};
            unsigned short hs[8], ls[8];
#pragma unroll
            for (int j = 0; j < 8; ++j) {
                float p = __expf(sv[j] - mr) * ir;
                unsigned short hb = f2bu(p);
                hs[j] = hb; ls[j] = f2bu(p - bu2f(hb));
            }
            *(uint4*)&Ahi[ar][aks] = *(uint4*)hs;
            *(uint4*)&Alo[ar][aks] = *(uint4*)ls;
        }
        {   // B tiles: direct copy
            unsigned short* dh = vhalf ? &Blo[vd][vks] : &Bhi[vd][vks];
            *(uint4*)dh       = vb0;
            *(uint4*)(dh + 8) = vb1;
        }
        __syncthreads();
        if (kc + 32 < NN) {
            sa0 = *(const float4*)(Ap + kc + 32);
            sa1 = *(const float4*)(Ap + kc + 36);
            vb0 = *(const uint4*)(Vp + kc + 32);
            vb1 = *(const uint4*)(Vp + kc + 40);
        }
        bf16x8 ah = *(const bf16x8*)&Ahi[wid*16 + lr][lkg*8];
        bf16x8 al = *(const bf16x8*)&Alo[wid*16 + lr][lkg*8];
#pragma unroll
        for (int n = 0; n < 4; ++n) {
            bf16x8 bhv = *(const bf16x8*)&Bhi[n*16 + lr][lkg*8];
            bf16x8 blv = *(const bf16x8*)&Blo[n*16 + lr][lkg*8];
            acc[n] = __builtin_amdgcn_mfma_f32_16x16x32_bf16(ah, bhv, acc[n], 0, 0, 0);
            acc[n] = __builtin_amdgcn_mfma_f32_16x16x32_bf16(al, bhv, acc[n], 0, 0, 0);
            acc[n] = __builtin_amdgcn_mfma_f32_16x16x32_bf16(ah, blv, acc[n], 0, 0, 0);
            acc[n] = __builtin_amdgcn_mfma_f32_16x16x32_bf16(al, blv, acc[n], 0, 0, 0);
        }
    }
#pragma unroll
    for (int n = 0; n < 4; ++n)
#pragma unroll
        for (int r2 = 0; r2 < 4; ++r2) {
            int row = row0 + wid*16 + lkg*4 + r2;
            int col = n*16 + lr;
            float v = acc[n][r2];
            unsigned short hb = f2bu(v);
            unsigned short lb = f2bu(v - bu2f(hb));
            unsigned short* cp = (unsigned short*)ctxs + (size_t)(b*NN + row) * 1536 + h*64 + col;
            cp[0]   = hb;
            cp[768] = lb;
        }
}

// ---- Gate ----
__global__ __launch_bounds__(256) void gate_k(const float* __restrict__ x,
                                              const float* __restrict__ gw,
                                              int* __restrict__ idx1, int* __restrict__ idx2,
                                              float* __restrict__ g1n, float* __restrict__ g2n,
                                              float* __restrict__ proxy, float* __restrict__ cnt1) {
    __shared__ float gws[DD*EE];
    for (int i = threadIdx.x; i < DD*EE; i += 256) gws[i] = gw[i];
    __syncthreads();
    int t = blockIdx.x * 256 + threadIdx.x;
    int b = t >> 10;
    float acc[EE] = {};
    const float4* xp = (const float4*)(x + (size_t)t * DD);
    for (int d4 = 0; d4 < DD/4; ++d4) {
        float4 xv = xp[d4];
        float xs[4] = {xv.x, xv.y, xv.z, xv.w};
#pragma unroll
        for (int qq = 0; qq < 4; ++qq) {
            const float* g = &gws[(d4*4+qq)*EE];
#pragma unroll
            for (int e = 0; e < EE; ++e) acc[e] += xs[qq] * g[e];
        }
    }
    float m = acc[0];
#pragma unroll
    for (int e = 1; e < EE; ++e) m = fmaxf(m, acc[e]);
    float sum = 0.f;
    float raw[EE];
#pragma unroll
    for (int e = 0; e < EE; ++e) { raw[e] = expf(acc[e] - m); sum += raw[e]; }
    float inv = 1.0f / sum;
#pragma unroll
    for (int e = 0; e < EE; ++e) raw[e] *= inv;
    int i1 = 0; float p1 = raw[0];
#pragma unroll
    for (int e = 1; e < EE; ++e) if (raw[e] > p1) { p1 = raw[e]; i1 = e; }
    int i2 = (i1 == 0) ? 1 : 0; float p2 = raw[i2];
#pragma unroll
    for (int e = 0; e < EE; ++e) if (e != i1 && raw[e] > p2) { p2 = raw[e]; i2 = e; }
    float den = p1 + p2 + 1e-9f;
    idx1[t] = i1; idx2[t] = i2;
    g1n[t] = p1 / den; g2n[t] = p2 / den;
    int ln = threadIdx.x & 63;
#pragma unroll
    for (int e = 0; e < EE; ++e) {
        float r = raw[e];
#pragma unroll
        for (int off = 1; off < 64; off <<= 1) r += __shfl_xor(r, off);
        if (ln == 0) atomicAdd(&proxy[b*EE + e], r);
    }
#pragma unroll
    for (int e = 0; e < EE; ++e) {
        unsigned long long mb = __ballot(i1 == e);
        if (ln == 0 && mb) atomicAdd(&cnt1[b*EE + e], (float)__popcll(mb));
    }
}

// ---- Capacity: parallel prefix-scan per (b,e); order-identical to serial ----
__global__ __launch_bounds__(256) void capacity_k(const int* __restrict__ idx1, const int* __restrict__ idx2,
                           const float* __restrict__ g1n, const float* __restrict__ g2n,
                           float* __restrict__ g1k, float* __restrict__ g2k,
                           int* __restrict__ pos1, int* __restrict__ pos2,
                           int* __restrict__ tokslot) {
    const int b = blockIdx.x >> 4, e = blockIdx.x & 15;
    const int tid = threadIdx.x, lane = tid & 63, wv = tid >> 6;
    const int base = b * NN;
    const int n0 = tid * 4;
    __shared__ int wsum[4];
    __shared__ int totsh;

    int4 iv = *(const int4*)(idx1 + base + n0);
    int id[4] = {iv.x, iv.y, iv.z, iv.w};
    int cnt = 0;
#pragma unroll
    for (int j = 0; j < 4; ++j) cnt += (id[j] == e);
    int v = cnt;
#pragma unroll
    for (int off = 1; off < 64; off <<= 1) {
        int o = __shfl_up(v, off);
        if (lane >= off) v += o;
    }
    if (lane == 63) wsum[wv] = v;
    __syncthreads();
    int woff = 0;
#pragma unroll
    for (int w = 0; w < 4; ++w) if (w < wv) woff += wsum[w];
    int c = woff + v - cnt;
    if (tid == 255) totsh = woff + v;
#pragma unroll
    for (int j = 0; j < 4; ++j) {
        if (id[j] == e) {
            int t = base + n0 + j;
            if (c < CAPX) {
                g1k[t] = g1n[t]; pos1[t] = c;
                tokslot[(e*BB + b)*CAPX + c] = t;
            } else { g1k[t] = 0.f; pos1[t] = 0; }
            c++;
        }
    }
    __syncthreads();
    const int m1c = totsh < CAPX ? totsh : CAPX;

    iv = *(const int4*)(idx2 + base + n0);
    int id2[4] = {iv.x, iv.y, iv.z, iv.w};
    cnt = 0;
#pragma unroll
    for (int j = 0; j < 4; ++j) cnt += (id2[j] == e);
    v = cnt;
#pragma unroll
    for (int off = 1; off < 64; off <<= 1) {
        int o = __shfl_up(v, off);
        if (lane >= off) v += o;
    }
    if (lane == 63) wsum[wv] = v;
    __syncthreads();
    woff = 0;
#pragma unroll
    for (int w = 0; w < 4; ++w) if (w < wv) woff += wsum[w];
    c = woff + v - cnt + m1c;
#pragma unroll
    for (int j = 0; j < 4; ++j) {
        if (id2[j] == e) {
            int t = base + n0 + j;
            if (c < CAPX) {
                g2k[t] = g2n[t]; pos2[t] = c;
                tokslot[(e*BB + b)*CAPX + c] = t;
            } else { g2k[t] = 0.f; pos2[t] = 0; }
            c++;
        }
    }
}

// ---- Gather tokens into expert slots (zero-fill empty slots) ----
__global__ __launch_bounds__(256) void gather_k(const float* __restrict__ x,
                                                const int* __restrict__ tokslot,
                                                __hip_bfloat16* __restrict__ xin) {
    int sid = blockIdx.x;
    int t = tokslot[sid];
    __hip_bfloat16* op = xin + (size_t)sid * DD;
    if (t >= 0) {
        const float* xp = x + (size_t)t * DD;
        for (int d = threadIdx.x; d < DD; d += 256) op[d] = f2b(xp[d]);
    } else {
        for (int d = threadIdx.x; d < DD; d += 256) op[d] = f2b(0.f);
    }
}

// ---- Final combine: out(fp32) = h + g1*xo[e1,slot1] + g2*xo[e2,slot2] ----
__global__ __launch_bounds__(256) void combine_k(const float* __restrict__ h,
                                                 const __hip_bfloat16* __restrict__ xo,
                                                 const int* __restrict__ idx1, const int* __restrict__ idx2,
                                                 const int* __restrict__ pos1, const int* __restrict__ pos2,
                                                 const float* __restrict__ g1k, const float* __restrict__ g2k,
                                                 float* __restrict__ out) {
    int t = blockIdx.x;
    int b = t >> 10;
    float ga = g1k[t], gb = g2k[t];
    const __hip_bfloat16* xa = nullptr;
    const __hip_bfloat16* xb = nullptr;
    if (ga > 0.f) xa = xo + (size_t)((idx1[t]*BB + b)*CAPX + pos1[t]) * DD;
    if (gb > 0.f) xb = xo + (size_t)((idx2[t]*BB + b)*CAPX + pos2[t]) * DD;
    const float* hp = h + (size_t)t * DD;
    float* op = out + (size_t)t * DD;
    for (int d = threadIdx.x; d < DD; d += 256) {
        float v = hp[d];
        if (xa) v += ga * b2f(xa[d]);
        if (xb) v += gb * b2f(xb[d]);
        op[d] = v;
    }
}

// ---- Aux loss ----
__global__ void loss_k(const float* __restrict__ proxy, const float* __restrict__ cnt1,
                       float* __restrict__ out_loss) {
    int tid = threadIdx.x;
    float v = proxy[tid] * cnt1[tid];
#pragma unroll
    for (int off = 1; off < 64; off <<= 1) v += __shfl_xor(v, off);
    __shared__ float sm[2];
    if ((tid & 63) == 0) sm[tid >> 6] = v;
    __syncthreads();
    if (tid == 0) {
        float tot = sm[0] + sm[1];
        float loss = tot * (0.02f / (1024.f * 1024.f));
        *out_loss = loss;
    }
}

extern "C" void kernel_launch(void* const* d_in, const int* in_sizes, int n_in,
                              void* d_out, int out_size, void* d_ws, size_t ws_size,
                              hipStream_t stream) {
    const float* hid = (const float*)d_in[0];
    const float* ln0 = (const float*)d_in[2];
    const float* Wq  = (const float*)d_in[3];
    const float* Wk  = (const float*)d_in[4];
    const float* Wv  = (const float*)d_in[5];
    const float* Wo  = (const float*)d_in[6];
    const float* ln1 = (const float*)d_in[7];
    const float* gw  = (const float*)d_in[8];
    const float* w1  = (const float*)d_in[9];
    const float* w2  = (const float*)d_in[10];
    float* out = (float*)d_out;

    // ---- Workspace: 7 x SZ regions (~176.6 MB). Liveness plan:
    //  R1: nsplit -> Vt2 -> wT(FFN, spans R1+R2)
    //  R2: wtbufQKV(7.1MB) -> S_c part -> wtbufO(2.4MB) -> wT part
    //  R3: S_c part -> hffn(lo)
    //  R4: vf -> S_c part -> hffn(hi)
    //  R5: Aq2 -> hres (live to end)
    //  R6: Bk2 -> normed2 -> xo
    //  R7: csplit -> xin
    const size_t SZ = (size_t)NT * DD * 4;
    char* p = (char*)d_ws;
    auto alloc = [&](size_t bytes) { char* r = p; p += (bytes + 255) & ~(size_t)255; return (void*)r; };
    char* R1 = (char*)alloc(SZ);
    char* R2 = (char*)alloc(SZ);
    char* R3 = (char*)alloc(SZ);
    char* R4 = (char*)alloc(SZ);
    char* R5 = (char*)alloc(SZ);
    char* R6 = (char*)alloc(SZ);
    char* R7 = (char*)alloc(SZ);
    int*   idx1 = (int*)alloc(NT*4);
    int*   idx2 = (int*)alloc(NT*4);
    float* g1n  = (float*)alloc(NT*4);
    float* g2n  = (float*)alloc(NT*4);
    float* g1k  = (float*)alloc(NT*4);
    float* g2k  = (float*)alloc(NT*4);
    int*   pos1 = (int*)alloc(NT*4);
    int*   pos2 = (int*)alloc(NT*4);
    int*   tokslot = (int*)alloc(EE*BB*CAPX*4);
    float* proxy   = (float*)alloc(BB*EE*4);
    float* cnt1f   = (float*)alloc(BB*EE*4);
    size_t needed = (size_t)(p - (char*)d_ws);
    if (needed > ws_size) return;

    __hip_bfloat16* nsplit   = (__hip_bfloat16*)R1;
    __hip_bfloat16* wtbufQKV = (__hip_bfloat16*)R2;  // 2304x1536 bf16 = 7.08MB
    float*          vf       = (float*)R4;
    __hip_bfloat16* Aq2      = (__hip_bfloat16*)R5;
    __hip_bfloat16* Bk2      = (__hip_bfloat16*)R6;
    __hip_bfloat16* Vt2      = (__hip_bfloat16*)R1;  // nsplit dead after QKV gemm
    float*          S_c      = (float*)R2;           // spans R2..R4 (16 heads = 64MB)
    __hip_bfloat16* csplit   = (__hip_bfloat16*)R7;
    __hip_bfloat16* wtbufO   = (__hip_bfloat16*)R2;  // S dead after last pv
    float*          hres     = (float*)R5;           // Aq2 dead after attention
    float*          normed2  = (float*)R6;           // Bk2 dead after attention
    __hip_bfloat16* wT       = (__hip_bfloat16*)R1;  // FFN: spans R1+R2
    __hip_bfloat16* hffn     = (__hip_bfloat16*)R3;  // FFN: spans R3+R4
    __hip_bfloat16* xo       = (__hip_bfloat16*)R6;  // normed2 dead after gather
    __hip_bfloat16* xin      = (__hip_bfloat16*)R7;  // csplit dead after O-proj

    (void)hipMemsetAsync(tokslot, 0xFF, EE*BB*CAPX*4, stream);
    (void)hipMemsetAsync(proxy, 0, BB*EE*4, stream);
    (void)hipMemsetAsync(cnt1f, 0, BB*EE*4, stream);

    // 1. RMSNorm(hidden) fused with hi/lo split pack
    rmsnorm_split_k<<<NT, 192, 0, stream>>>(hid, ln0, nsplit);
    // 2. Fused QKV projection (4-term split-bf16 MFMA, XCD-swizzled).
    //    Epilogue writes Q/K packed + V fp32; pack_qk eliminated.
    transpose_split3_k<<<dim3(DD/32, DD/32, 3), 256, 0, stream>>>(Wq, Wk, Wv, wtbufQKV);
    gemm_qkv_k<<<1152, 256, 0, stream>>>(nsplit, wtbufQKV, Aq2, Bk2, vf);
    // 3. Attention: pack V, then 6 chunks of 16 (b,h); S_c reused per chunk
    pack_v_k<<<dim3(NN/32, BB*HH), 256, 0, stream>>>(vf, Vt2);
    for (int c = 0; c < 6; ++c) {
        int bh0 = c * 16;
        attn_qk_k<<<dim3(NN/128, NN/128, 16), 256, 0, stream>>>(Aq2, Bk2, S_c, bh0);
        attn_pv_k<<<dim3(NN/64, 16), 256, 0, stream>>>(S_c, Vt2, csplit, bh0);
    }
    // 4. O-projection (split-bf16 MFMA, swizzled) + residual -> h (fp32)
    transpose_split_k<<<dim3(DD/32, DD/32), 256, 0, stream>>>(Wo, wtbufO);
    gemm_mfma4_k<<<384, 256, 0, stream>>>(csplit, wtbufO, hres, hid);
    // 5. RMSNorm(h) fp32
    rmsnorm_k<float><<<NT, 256, 0, stream>>>(hres, ln1, normed2);
    // 6. Gating
    gate_k<<<NT/256, 256, 0, stream>>>(normed2, gw, idx1, idx2, g1n, g2n, proxy, cnt1f);
    // 7. Capacity assignment (parallel prefix scan)
    capacity_k<<<BB*EE, 256, 0, stream>>>(idx1, idx2, g1n, g2n, g1k, g2k, pos1, pos2, tokslot);
    // 8. Gather into expert slots (fp32 -> bf16)
    gather_k<<<EE*BB*CAPX, 256, 0, stream>>>(normed2, tokslot, xin);
    // 9/10. Expert FFN via bf16 MFMA (XCD-swizzled: expert = XCD), 2 groups of 8
    for (int g = 0; g < 2; ++g) {
        const int e0 = g * 8;
        transpose_cvt_k<<<dim3(DFF/32, DD/32, 8), 256, 0, stream>>>(
            w1 + (size_t)e0*DD*DFF, wT, DD, DFF);
        gemm_mfma_k<true><<<(DFF/128)*((BB*CAPX)/128)*8, 256, 0, stream>>>(
            xin + (size_t)e0*BB*CAPX*DD, wT, hffn,
            DFF, DD, DFF/128,
            (long)BB*CAPX*DD, (long)DD*DFF, (long)BB*CAPX*DFF);
        transpose_cvt_k<<<dim3(DD/32, DFF/32, 8), 256, 0, stream>>>(
            w2 + (size_t)e0*DFF*DD, wT, DFF, DD);
        gemm_mfma_k<false><<<(DD/128)*((BB*CAPX)/128)*8, 256, 0, stream>>>(
            hffn, wT, xo + (size_t)e0*BB*CAPX*DD,
            DD, DFF, DD/128,
            (long)BB*CAPX*DFF, (long)DFF*DD, (long)BB*CAPX*DD);
    }
    // 11. Combine + residual -> output (fp32)
    combine_k<<<NT, 256, 0, stream>>>(hres, xo, idx1, idx2, pos1, pos2, g1k, g2k, out);
    // 12. Aux loss scalar (fp32)
    loss_k<<<1, 128, 0, stream>>>(proxy, cnt1f, out + (size_t)NT*DD);
}